// Round 10
// baseline (147.572 us; speedup 1.0000x reference)
//
#include <hip/hip_runtime.h>
#include <math.h>

#define B_   128
#define T_   1024
#define D_   256
#define L_   512

__device__ __forceinline__ float sigmoidf_(float x) {
    return 1.f / (1.f + __expf(-x));
}
__device__ __forceinline__ float tanhf_(float x) {
    x = fminf(fmaxf(x, -15.f), 15.f);
    float e = __expf(2.f * x);
    return (e - 1.f) / (e + 1.f);
}
// tanh(x) = 1 - 2/(exp(2x)+1); exact identity, v_exp + v_rcp
__device__ __forceinline__ float tanh_fast(float x) {
    float e = __expf(2.f * x);
    return 1.f - 2.f * __builtin_amdgcn_rcpf(e + 1.f);
}
__device__ __forceinline__ float waveReduceSum(float v) {
    #pragma unroll
    for (int o = 32; o > 0; o >>= 1) v += __shfl_xor(v, o, 64);
    return v;
}
__device__ __forceinline__ float waveReduceMax(float v) {
    #pragma unroll
    for (int o = 32; o > 0; o >>= 1) v = fmaxf(v, __shfl_xor(v, o, 64));
    return v;
}

// ---------------------------------------------------------------------------
// K1b fused: prenet (recomputed per block, cheap) + GRU gate GEMVs.
// grid = (3 j-tiles, 64 batch-pairs), block = 256.
// ---------------------------------------------------------------------------
__global__ __launch_bounds__(256) void k1b_fused(
    const float* __restrict__ prenet_in, const float* __restrict__ context_vec,
    const float* __restrict__ attn_hidden,
    const float* __restrict__ fc1_W, const float* __restrict__ fc1_b,
    const float* __restrict__ fc2_W, const float* __restrict__ fc2_b,
    const float* __restrict__ gru_Wih, const float* __restrict__ gru_Whh,
    const float* __restrict__ gru_bih, const float* __restrict__ gru_bhh,
    float* __restrict__ gi_out, float* __restrict__ gh_out)
{
    const int t = threadIdx.x;
    const int j = blockIdx.x * 256 + t;
    const int b0 = blockIdx.y * 2;

    __shared__ __align__(16) float pin[2][80];
    __shared__ __align__(16) float p1[2][256];
    __shared__ __align__(16) float xs[2][384];   // [cvec | prenet_out]
    __shared__ __align__(16) float hs[2][256];

    if (t < 160) pin[t / 80][t % 80] = prenet_in[(b0 + t / 80) * 80 + (t % 80)];
    xs[0][t] = context_vec[b0 * 256 + t];
    xs[1][t] = context_vec[(b0 + 1) * 256 + t];
    hs[0][t] = attn_hidden[b0 * 256 + t];
    hs[1][t] = attn_hidden[(b0 + 1) * 256 + t];
    __syncthreads();

    // fc1: 256 outputs x 2 batches, K=80
    {
        float a0 = fc1_b[t], a1 = a0;
        const float4* w  = (const float4*)(fc1_W + t * 80);
        const float4* x0 = (const float4*)pin[0];
        const float4* x1 = (const float4*)pin[1];
        #pragma unroll
        for (int k = 0; k < 20; k++) {
            float4 wv = w[k], v0 = x0[k], v1 = x1[k];
            a0 += v0.x * wv.x + v0.y * wv.y + v0.z * wv.z + v0.w * wv.w;
            a1 += v1.x * wv.x + v1.y * wv.y + v1.z * wv.z + v1.w * wv.w;
        }
        p1[0][t] = fmaxf(a0, 0.f);
        p1[1][t] = fmaxf(a1, 0.f);
    }
    __syncthreads();

    // fc2: 128 outputs x 2 batches, K=256 (t<128 -> batch0, t>=128 -> batch1)
    {
        const int bb = t >> 7, jj = t & 127;
        float a = fc2_b[jj];
        const float4* w  = (const float4*)(fc2_W + jj * 256);
        const float4* xv = (const float4*)p1[bb];
        #pragma unroll 8
        for (int k = 0; k < 64; k++) {
            float4 wv = w[k], v = xv[k];
            a += v.x * wv.x + v.y * wv.y + v.z * wv.z + v.w * wv.w;
        }
        xs[bb][256 + jj] = fmaxf(a, 0.f);
    }
    __syncthreads();

    // gi: K=384
    {
        float a0 = gru_bih[j], a1 = a0;
        const float4* w  = (const float4*)(gru_Wih + (size_t)j * 384);
        const float4* x0 = (const float4*)xs[0];
        const float4* x1 = (const float4*)xs[1];
        #pragma unroll 8
        for (int k = 0; k < 96; k++) {
            float4 wv = w[k], v0 = x0[k], v1 = x1[k];
            a0 += v0.x * wv.x + v0.y * wv.y + v0.z * wv.z + v0.w * wv.w;
            a1 += v1.x * wv.x + v1.y * wv.y + v1.z * wv.z + v1.w * wv.w;
        }
        gi_out[(size_t)(b0 + 0) * 768 + j] = a0;
        gi_out[(size_t)(b0 + 1) * 768 + j] = a1;
    }
    // gh: K=256
    {
        float a0 = gru_bhh[j], a1 = a0;
        const float4* w  = (const float4*)(gru_Whh + (size_t)j * 256);
        const float4* x0 = (const float4*)hs[0];
        const float4* x1 = (const float4*)hs[1];
        #pragma unroll 8
        for (int k = 0; k < 64; k++) {
            float4 wv = w[k], v0 = x0[k], v1 = x1[k];
            a0 += v0.x * wv.x + v0.y * wv.y + v0.z * wv.z + v0.w * wv.w;
            a1 += v1.x * wv.x + v1.y * wv.y + v1.z * wv.z + v1.w * wv.w;
        }
        gh_out[(size_t)(b0 + 0) * 768 + j] = a0;
        gh_out[(size_t)(b0 + 1) * 768 + j] = a1;
    }
}

// ---------------------------------------------------------------------------
// K1c: GRU gates + q = attn_h @ attn_W.T.   grid=128, block=256
// ---------------------------------------------------------------------------
__global__ __launch_bounds__(256) void k1c_gates_q(
    const float* __restrict__ gi, const float* __restrict__ gh,
    const float* __restrict__ attn_hidden, const float* __restrict__ attn_W,
    float* __restrict__ attn_h_out, float* __restrict__ q_out)
{
    const int b = blockIdx.x, t = threadIdx.x;
    __shared__ __align__(16) float ahn[256];

    {
        float hp = attn_hidden[b * 256 + t];
        float rg = sigmoidf_(gi[(size_t)b * 768 + t]       + gh[(size_t)b * 768 + t]);
        float zg = sigmoidf_(gi[(size_t)b * 768 + 256 + t] + gh[(size_t)b * 768 + 256 + t]);
        float ng = tanhf_(gi[(size_t)b * 768 + 512 + t] + rg * gh[(size_t)b * 768 + 512 + t]);
        float h  = (1.f - zg) * ng + zg * hp;
        ahn[t] = h;
        attn_h_out[b * 256 + t] = h;
    }
    __syncthreads();

    {
        float a = 0.f;
        const float4* w  = (const float4*)(attn_W + (size_t)t * 256);
        const float4* xv = (const float4*)ahn;
        #pragma unroll 8
        for (int k = 0; k < 64; k++) {
            float4 wv = w[k], v = xv[k];
            a += v.x * wv.x + v.y * wv.y + v.z * wv.z + v.w * wv.w;
        }
        q_out[b * 256 + t] = a;
    }
}

// ---------------------------------------------------------------------------
// KA: fused attention (R4-measured structure, CORRECT full-256-col stage 1,
// + T14 prefetch: 8 enc rows loaded into registers during stage 1/2 so the
// two streams overlap).  grid = B*16 chunks of 64 t, block=256 (4 waves).
// ---------------------------------------------------------------------------
__global__ __launch_bounds__(256, 4) void ka_attn(
    const float* __restrict__ enc_proj, const float* __restrict__ enc,
    const float* __restrict__ q, const float* __restrict__ v,
    float* __restrict__ u_out, float* __restrict__ ctx_part,
    float* __restrict__ m_part, float* __restrict__ s_part)
{
    const int b     = blockIdx.x >> 4;
    const int chunk = blockIdx.x & 15;
    const int tid   = threadIdx.x;
    const int lane  = tid & 63;
    const int wv    = tid >> 6;    // 0..3
    const int g     = lane >> 4;   // 16-lane group 0..3
    const int gl    = lane & 15;

    __shared__ float ul[64];
    __shared__ float el[64];
    __shared__ __align__(16) float4 red[4][64];

    const int t0 = chunk * 64;

    // per-lane copies of q,v covering all 4 d-chunks of 64
    float4 qv[4], vv[4];
    #pragma unroll
    for (int c = 0; c < 4; c++) {
        qv[c] = ((const float4*)(q + b * 256))[c * 16 + gl];
        vv[c] = ((const float4*)v)[c * 16 + gl];
    }

    // ---- stage 1: u for 64 t's (16-lane group owns one t per pass) ----
    const float* ebase = enc_proj + ((size_t)(b * T_ + t0)) * 256;
    #pragma unroll
    for (int pass = 0; pass < 4; pass++) {
        const int t = wv * 16 + pass * 4 + g;
        const float4* row = (const float4*)(ebase + (size_t)t * 256);
        float s = 0.f;
        #pragma unroll
        for (int c = 0; c < 4; c++) {
            float4 pj = row[c * 16 + gl];
            s += tanh_fast(pj.x + qv[c].x) * vv[c].x
               + tanh_fast(pj.y + qv[c].y) * vv[c].y
               + tanh_fast(pj.z + qv[c].z) * vv[c].z
               + tanh_fast(pj.w + qv[c].w) * vv[c].w;
        }
        s += __shfl_xor(s, 1, 64);
        s += __shfl_xor(s, 2, 64);
        s += __shfl_xor(s, 4, 64);
        s += __shfl_xor(s, 8, 64);
        if (gl == 0) ul[t] = s;
    }

    // T14 prefetch: issue first 8 enc rows of this wave's 16 now; the loads
    // stay in flight across the barriers and stage 2's VALU work.
    const float4* base2 = (const float4*)(enc + ((size_t)(b * T_ + t0)) * 256);
    float4 pre[8];
    #pragma unroll
    for (int i = 0; i < 8; i++)
        pre[i] = base2[(size_t)(wv * 16 + i) * 64 + lane];

    __syncthreads();

    // ---- stage 2 (wave 0 only): chunk-local max / exp / sum ----
    if (wv == 0) {
        float x = ul[lane];
        u_out[b * T_ + t0 + lane] = x;
        float mx = waveReduceMax(x);
        float e = __expf(x - mx);
        el[lane] = e;
        float ss = waveReduceSum(e);
        if (lane == 0) {
            m_part[b * 16 + chunk] = mx;
            s_part[b * 16 + chunk] = ss;
        }
    }
    __syncthreads();

    // ---- stage 3: context partial, first 8 rows from prefetch regs ----
    float4 acc0 = {0.f, 0.f, 0.f, 0.f}, acc1 = {0.f, 0.f, 0.f, 0.f};
    #pragma unroll
    for (int i = 0; i < 8; i += 2) {
        float e0 = el[wv * 16 + i], e1 = el[wv * 16 + i + 1];
        acc0.x += e0 * pre[i].x;     acc0.y += e0 * pre[i].y;
        acc0.z += e0 * pre[i].z;     acc0.w += e0 * pre[i].w;
        acc1.x += e1 * pre[i + 1].x; acc1.y += e1 * pre[i + 1].y;
        acc1.z += e1 * pre[i + 1].z; acc1.w += e1 * pre[i + 1].w;
    }
    #pragma unroll
    for (int i = 8; i < 16; i += 2) {
        int t = wv * 16 + i;
        float e0 = el[t], e1 = el[t + 1];
        float4 v0 = base2[(size_t)t * 64 + lane];
        float4 v1 = base2[(size_t)(t + 1) * 64 + lane];
        acc0.x += e0 * v0.x; acc0.y += e0 * v0.y; acc0.z += e0 * v0.z; acc0.w += e0 * v0.w;
        acc1.x += e1 * v1.x; acc1.y += e1 * v1.y; acc1.z += e1 * v1.z; acc1.w += e1 * v1.w;
    }
    acc0.x += acc1.x; acc0.y += acc1.y; acc0.z += acc1.z; acc0.w += acc1.w;
    red[wv][lane] = acc0;
    __syncthreads();
    if (tid < 64) {
        float4 s = red[0][tid];
        float4 a1 = red[1][tid], a2 = red[2][tid], a3 = red[3][tid];
        s.x += a1.x + a2.x + a3.x;
        s.y += a1.y + a2.y + a3.y;
        s.z += a1.z + a2.z + a3.z;
        s.w += a1.w + a2.w + a3.w;
        ((float4*)ctx_part)[(size_t)(b * 16 + chunk) * 64 + tid] = s;
    }
}

// ---------------------------------------------------------------------------
// KB: combine 16 partials -> context, scores, concat1.  grid=128 (per batch)
// ---------------------------------------------------------------------------
__global__ __launch_bounds__(256) void kb_combine(
    const float* __restrict__ u, const float* __restrict__ m_part,
    const float* __restrict__ s_part, const float* __restrict__ ctx_part,
    const float* __restrict__ attn_h,
    float* __restrict__ scores_out, float* __restrict__ ctx_out,
    float* __restrict__ concat1)
{
    const int b = blockIdx.x, tid = threadIdx.x;
    __shared__ float msh[16], ssh[16];
    if (tid < 16) {
        msh[tid] = m_part[b * 16 + tid];
        ssh[tid] = s_part[b * 16 + tid];
    }
    __syncthreads();

    float M = msh[0];
    #pragma unroll
    for (int c = 1; c < 16; c++) M = fmaxf(M, msh[c]);
    float S = 0.f;
    #pragma unroll
    for (int c = 0; c < 16; c++) S += ssh[c] * __expf(msh[c] - M);
    float invS = 1.f / S;

    {
        float a = 0.f;
        #pragma unroll
        for (int c = 0; c < 16; c++)
            a += ctx_part[(size_t)(b * 16 + c) * 256 + tid] * __expf(msh[c] - M);
        a *= invS;
        ctx_out[b * 256 + tid] = a;
        concat1[b * 512 + tid] = a;
        concat1[b * 512 + 256 + tid] = attn_h[b * 256 + tid];
    }

    #pragma unroll
    for (int i = 0; i < 4; i++) {
        int t = i * 256 + tid;
        scores_out[b * T_ + t] = __expf(u[b * T_ + t] - M) * invS;
    }
}

// ---------------------------------------------------------------------------
// GEMM: part[z][m][n] = A_seg[m][k0:k0+KSZ] @ W_seg[n][k0:k0+KSZ]^T
// grid = (N/64, 2, nseg*ksPerSeg)
// ---------------------------------------------------------------------------
__global__ __launch_bounds__(256) void gemm512_splitk(
    const float* __restrict__ A1, const float* __restrict__ W1,
    const float* __restrict__ A2, const float* __restrict__ W2,
    float* __restrict__ part, int N, int ksPerSeg)
{
    const int n0 = blockIdx.x * 64, m0 = blockIdx.y * 64;
    const int seg = blockIdx.z / ksPerSeg, ls = blockIdx.z % ksPerSeg;
    const int KSZ = 512 / ksPerSeg;
    const float* A = seg ? A2 : A1;
    const float* W = seg ? W2 : W1;
    const int k0 = ls * KSZ;

    __shared__ __align__(16) float As[32][68];
    __shared__ __align__(16) float Ws[32][68];

    const int tid = threadIdx.x;
    const int tm = tid & 15, tn = tid >> 4;
    const int rs = tid >> 3, qs = tid & 7;

    float acc[4][4] = {};

    for (int kt = 0; kt < KSZ; kt += 32) {
        #pragma unroll
        for (int it = 0; it < 2; it++) {
            int r = rs + it * 32;
            float4 av = *(const float4*)(A + (size_t)(m0 + r) * 512 + k0 + kt + qs * 4);
            As[qs * 4 + 0][r] = av.x; As[qs * 4 + 1][r] = av.y;
            As[qs * 4 + 2][r] = av.z; As[qs * 4 + 3][r] = av.w;
            float4 wv = *(const float4*)(W + (size_t)(n0 + r) * 512 + k0 + kt + qs * 4);
            Ws[qs * 4 + 0][r] = wv.x; Ws[qs * 4 + 1][r] = wv.y;
            Ws[qs * 4 + 2][r] = wv.z; Ws[qs * 4 + 3][r] = wv.w;
        }
        __syncthreads();
        #pragma unroll
        for (int kk = 0; kk < 32; kk++) {
            float4 a = *(const float4*)&As[kk][tm * 4];
            float4 w = *(const float4*)&Ws[kk][tn * 4];
            acc[0][0] += a.x * w.x; acc[0][1] += a.x * w.y; acc[0][2] += a.x * w.z; acc[0][3] += a.x * w.w;
            acc[1][0] += a.y * w.x; acc[1][1] += a.y * w.y; acc[1][2] += a.y * w.z; acc[1][3] += a.y * w.w;
            acc[2][0] += a.z * w.x; acc[2][1] += a.z * w.y; acc[2][2] += a.z * w.z; acc[2][3] += a.z * w.w;
            acc[3][0] += a.w * w.x; acc[3][1] += a.w * w.y; acc[3][2] += a.w * w.z; acc[3][3] += a.w * w.w;
        }
        __syncthreads();
    }

    float* pb = part + ((size_t)blockIdx.z * 128 + m0) * N + n0;
    #pragma unroll
    for (int i = 0; i < 4; i++) {
        float4 o = {acc[i][0], acc[i][1], acc[i][2], acc[i][3]};
        *(float4*)(pb + (size_t)(tm * 4 + i) * N + tn * 4) = o;
    }
}

// ---------------------------------------------------------------------------
// E_rnn: x = sum_z part[z] + bias     (N=512, 16 slices)
// ---------------------------------------------------------------------------
__global__ __launch_bounds__(256) void e_rnn(
    const float* __restrict__ part, const float* __restrict__ bias,
    float* __restrict__ x)
{
    const int idx = blockIdx.x * 256 + threadIdx.x;
    const int n = idx & 511;
    float a = bias[n];
    #pragma unroll
    for (int z = 0; z < 16; z++) a += part[(size_t)z * 65536 + idx];
    x[idx] = a;
}

// ---------------------------------------------------------------------------
// E_lstm: gate reduce (16 slices, N=2048) + LSTM cell + x_new = x_prev + h
// ---------------------------------------------------------------------------
__global__ __launch_bounds__(256) void e_lstm(
    const float* __restrict__ part,
    const float* __restrict__ bih, const float* __restrict__ bhh,
    const float* __restrict__ c_prev, const float* __restrict__ x_prev,
    float* __restrict__ h_out, float* __restrict__ c_out, float* __restrict__ x_new)
{
    const int idx = blockIdx.x * 256 + threadIdx.x;
    const int bb = idx >> 9, j = idx & 511;
    float gi = bih[j] + bhh[j];
    float gf = bih[512 + j] + bhh[512 + j];
    float gg = bih[1024 + j] + bhh[1024 + j];
    float go = bih[1536 + j] + bhh[1536 + j];
    #pragma unroll
    for (int z = 0; z < 16; z++) {
        const float* p = part + ((size_t)z * 128 + bb) * 2048;
        gi += p[j]; gf += p[512 + j]; gg += p[1024 + j]; go += p[1536 + j];
    }
    float c = sigmoidf_(gf) * c_prev[idx] + sigmoidf_(gi) * tanhf_(gg);
    float h = sigmoidf_(go) * tanhf_(c);
    h_out[idx] = h;
    c_out[idx] = c;
    x_new[idx] = x_prev[idx] + h;
}

// ---------------------------------------------------------------------------
// E_lstm2 + mel: grid=128 (per batch), block=512. x3 stays in LDS.
// ---------------------------------------------------------------------------
__global__ __launch_bounds__(512) void e_lstm2_mel(
    const float* __restrict__ part,
    const float* __restrict__ bih, const float* __restrict__ bhh,
    const float* __restrict__ c_prev, const float* __restrict__ x_prev,
    const float* __restrict__ mel_W, const int* __restrict__ r_ptr,
    float* __restrict__ h_out, float* __restrict__ c_out,
    float* __restrict__ mels)
{
    const int b = blockIdx.x, j = threadIdx.x;
    __shared__ __align__(16) float xs[512];

    const int idx = b * 512 + j;
    float gi = bih[j] + bhh[j];
    float gf = bih[512 + j] + bhh[512 + j];
    float gg = bih[1024 + j] + bhh[1024 + j];
    float go = bih[1536 + j] + bhh[1536 + j];
    #pragma unroll
    for (int z = 0; z < 16; z++) {
        const float* p = part + ((size_t)z * 128 + b) * 2048;
        gi += p[j]; gf += p[512 + j]; gg += p[1024 + j]; go += p[1536 + j];
    }
    float c = sigmoidf_(gf) * c_prev[idx] + sigmoidf_(gi) * tanhf_(gg);
    float h = sigmoidf_(go) * tanhf_(c);
    h_out[idx] = h;
    c_out[idx] = c;
    xs[j] = x_prev[idx] + h;
    __syncthreads();

    const int r = r_ptr[0];
    const int tot = 80 * r;
    for (int n = j; n < tot; n += 512) {
        int m = n / r, rr = n % r;
        const float4* w  = (const float4*)(mel_W + (size_t)(m * 20 + rr) * 512);
        const float4* xv = (const float4*)xs;
        float a = 0.f;
        #pragma unroll 8
        for (int k = 0; k < 128; k++) {
            float4 wv = w[k], vv = xv[k];
            a += wv.x * vv.x + wv.y * vv.y + wv.z * vv.z + wv.w * vv.w;
        }
        mels[(size_t)b * tot + n] = a;
    }
}

// ---------------------------------------------------------------------------
extern "C" void kernel_launch(void* const* d_in, const int* in_sizes, int n_in,
                              void* d_out, int out_size, void* d_ws, size_t ws_size,
                              hipStream_t stream)
{
    const float* enc   = (const float*)d_in[0];
    const float* encp  = (const float*)d_in[1];
    const float* pre   = (const float*)d_in[2];
    const float* ah_in = (const float*)d_in[3];
    const float* r1h   = (const float*)d_in[4];
    const float* r2h   = (const float*)d_in[5];
    const float* r1c   = (const float*)d_in[6];
    const float* r2c   = (const float*)d_in[7];
    const float* cvec  = (const float*)d_in[8];
    const float* fc1W  = (const float*)d_in[9];
    const float* fc1b  = (const float*)d_in[10];
    const float* fc2W  = (const float*)d_in[11];
    const float* fc2b  = (const float*)d_in[12];
    const float* attnW = (const float*)d_in[13];
    const float* attnv = (const float*)d_in[14];
    const float* gWih  = (const float*)d_in[15];
    const float* gWhh  = (const float*)d_in[16];
    const float* gbih  = (const float*)d_in[17];
    const float* gbhh  = (const float*)d_in[18];
    const float* rinW  = (const float*)d_in[19];
    const float* rinb  = (const float*)d_in[20];
    const float* l1Wih = (const float*)d_in[21];
    const float* l1Whh = (const float*)d_in[22];
    const float* l1bih = (const float*)d_in[23];
    const float* l1bhh = (const float*)d_in[24];
    const float* l2Wih = (const float*)d_in[25];
    const float* l2Whh = (const float*)d_in[26];
    const float* l2bih = (const float*)d_in[27];
    const float* l2bhh = (const float*)d_in[28];
    const float* melW  = (const float*)d_in[29];
    const int*   rp    = (const int*)d_in[30];

    float* out = (float*)d_out;
    float* o_mels  = out + 0;        // 128*80*2
    float* o_scor  = out + 20480;    // 128*1024
    float* o_attnh = out + 151552;   // 128*256
    float* o_r1h   = out + 184320;   // 128*512
    float* o_r2h   = out + 249856;
    float* o_r1c   = out + 315392;
    float* o_r2c   = out + 380928;
    float* o_ctx   = out + 446464;   // 128*256

    float* ws     = (float*)d_ws;
    float* w_q    = ws + 0;          // 32768
    float* w_u    = ws + 32768;      // 131072
    float* w_m    = ws + 163840;     // 2048
    float* w_s    = ws + 165888;     // 2048
    float* w_ctxp = ws + 167936;     // 16*128*256 = 524288
    float* w_cat1 = ws + 692224;     // 65536
    float* w_x    = ws + 757760;     // 65536
    float* w_x2   = ws + 823296;     // 65536
    float* w_part = ws + 888832;     // 16*128*2048 = 4194304 max

    // front-end scratch reuses the w_part region (free until the GEMM phase)
    float* w_gi = w_part;            // 128*768
    float* w_gh = w_part + 98304;    // 128*768

    hipLaunchKernelGGL(k1b_fused, dim3(3, 64), dim3(256), 0, stream,
                       pre, cvec, ah_in, fc1W, fc1b, fc2W, fc2b,
                       gWih, gWhh, gbih, gbhh, w_gi, w_gh);

    hipLaunchKernelGGL(k1c_gates_q, dim3(128), dim3(256), 0, stream,
                       w_gi, w_gh, ah_in, attnW, o_attnh, w_q);

    hipLaunchKernelGGL(ka_attn, dim3(2048), dim3(256), 0, stream,
                       encp, enc, w_q, attnv, w_u, w_ctxp, w_m, w_s);

    hipLaunchKernelGGL(kb_combine, dim3(128), dim3(256), 0, stream,
                       w_u, w_m, w_s, w_ctxp, o_attnh, o_scor, o_ctx, w_cat1);

    // rnn_in: K=512, 16 k-slices -> 256 blocks
    hipLaunchKernelGGL(gemm512_splitk, dim3(8, 2, 16), dim3(256), 0, stream,
                       w_cat1, rinW, w_cat1, rinW, w_part, 512, 16);
    hipLaunchKernelGGL(e_rnn, dim3(256), dim3(256), 0, stream, w_part, rinb, w_x);

    // LSTM 1: 2 segments x 8 k-slices -> 1024 blocks (4/CU)
    hipLaunchKernelGGL(gemm512_splitk, dim3(32, 2, 16), dim3(256), 0, stream,
                       w_x, l1Wih, r1h, l1Whh, w_part, 2048, 8);
    hipLaunchKernelGGL(e_lstm, dim3(256), dim3(256), 0, stream,
                       w_part, l1bih, l1bhh, r1c, w_x, o_r1h, o_r1c, w_x2);

    // LSTM 2 + mel
    hipLaunchKernelGGL(gemm512_splitk, dim3(32, 2, 16), dim3(256), 0, stream,
                       w_x2, l2Wih, r2h, l2Whh, w_part, 2048, 8);
    hipLaunchKernelGGL(e_lstm2_mel, dim3(128), dim3(512), 0, stream,
                       w_part, l2bih, l2bhh, r2c, w_x2, melW, rp,
                       o_r2h, o_r2c, o_mels);
}

// Round 11
// 144.064 us; speedup vs baseline: 1.0244x; 1.0244x over previous
//
#include <hip/hip_runtime.h>
#include <math.h>

#define B_   128
#define T_   1024
#define D_   256
#define L_   512

__device__ __forceinline__ float sigmoidf_(float x) {
    return 1.f / (1.f + __expf(-x));
}
__device__ __forceinline__ float tanhf_(float x) {
    x = fminf(fmaxf(x, -15.f), 15.f);
    float e = __expf(2.f * x);
    return (e - 1.f) / (e + 1.f);
}
// tanh(x) = 1 - 2/(exp(2x)+1); exact identity, v_exp + v_rcp
__device__ __forceinline__ float tanh_fast(float x) {
    float e = __expf(2.f * x);
    return 1.f - 2.f * __builtin_amdgcn_rcpf(e + 1.f);
}
__device__ __forceinline__ float waveReduceSum(float v) {
    #pragma unroll
    for (int o = 32; o > 0; o >>= 1) v += __shfl_xor(v, o, 64);
    return v;
}
__device__ __forceinline__ float waveReduceMax(float v) {
    #pragma unroll
    for (int o = 32; o > 0; o >>= 1) v = fmaxf(v, __shfl_xor(v, o, 64));
    return v;
}

// non-temporal float4 load: no-L3-allocate stream (protects the other
// stream's residency)
typedef float f4v __attribute__((ext_vector_type(4)));
__device__ __forceinline__ float4 nt_load4(const float4* p) {
    f4v v = __builtin_nontemporal_load((const f4v*)p);
    return make_float4(v.x, v.y, v.z, v.w);
}

// ---------------------------------------------------------------------------
// K1b fused: prenet (recomputed per block, cheap) + GRU gate GEMVs.
// grid = (3 j-tiles, 64 batch-pairs), block = 256.
// ---------------------------------------------------------------------------
__global__ __launch_bounds__(256) void k1b_fused(
    const float* __restrict__ prenet_in, const float* __restrict__ context_vec,
    const float* __restrict__ attn_hidden,
    const float* __restrict__ fc1_W, const float* __restrict__ fc1_b,
    const float* __restrict__ fc2_W, const float* __restrict__ fc2_b,
    const float* __restrict__ gru_Wih, const float* __restrict__ gru_Whh,
    const float* __restrict__ gru_bih, const float* __restrict__ gru_bhh,
    float* __restrict__ gi_out, float* __restrict__ gh_out)
{
    const int t = threadIdx.x;
    const int j = blockIdx.x * 256 + t;
    const int b0 = blockIdx.y * 2;

    __shared__ __align__(16) float pin[2][80];
    __shared__ __align__(16) float p1[2][256];
    __shared__ __align__(16) float xs[2][384];   // [cvec | prenet_out]
    __shared__ __align__(16) float hs[2][256];

    if (t < 160) pin[t / 80][t % 80] = prenet_in[(b0 + t / 80) * 80 + (t % 80)];
    xs[0][t] = context_vec[b0 * 256 + t];
    xs[1][t] = context_vec[(b0 + 1) * 256 + t];
    hs[0][t] = attn_hidden[b0 * 256 + t];
    hs[1][t] = attn_hidden[(b0 + 1) * 256 + t];
    __syncthreads();

    // fc1: 256 outputs x 2 batches, K=80
    {
        float a0 = fc1_b[t], a1 = a0;
        const float4* w  = (const float4*)(fc1_W + t * 80);
        const float4* x0 = (const float4*)pin[0];
        const float4* x1 = (const float4*)pin[1];
        #pragma unroll
        for (int k = 0; k < 20; k++) {
            float4 wv = w[k], v0 = x0[k], v1 = x1[k];
            a0 += v0.x * wv.x + v0.y * wv.y + v0.z * wv.z + v0.w * wv.w;
            a1 += v1.x * wv.x + v1.y * wv.y + v1.z * wv.z + v1.w * wv.w;
        }
        p1[0][t] = fmaxf(a0, 0.f);
        p1[1][t] = fmaxf(a1, 0.f);
    }
    __syncthreads();

    // fc2: 128 outputs x 2 batches, K=256 (t<128 -> batch0, t>=128 -> batch1)
    {
        const int bb = t >> 7, jj = t & 127;
        float a = fc2_b[jj];
        const float4* w  = (const float4*)(fc2_W + jj * 256);
        const float4* xv = (const float4*)p1[bb];
        #pragma unroll 8
        for (int k = 0; k < 64; k++) {
            float4 wv = w[k], v = xv[k];
            a += v.x * wv.x + v.y * wv.y + v.z * wv.z + v.w * wv.w;
        }
        xs[bb][256 + jj] = fmaxf(a, 0.f);
    }
    __syncthreads();

    // gi: K=384
    {
        float a0 = gru_bih[j], a1 = a0;
        const float4* w  = (const float4*)(gru_Wih + (size_t)j * 384);
        const float4* x0 = (const float4*)xs[0];
        const float4* x1 = (const float4*)xs[1];
        #pragma unroll 8
        for (int k = 0; k < 96; k++) {
            float4 wv = w[k], v0 = x0[k], v1 = x1[k];
            a0 += v0.x * wv.x + v0.y * wv.y + v0.z * wv.z + v0.w * wv.w;
            a1 += v1.x * wv.x + v1.y * wv.y + v1.z * wv.z + v1.w * wv.w;
        }
        gi_out[(size_t)(b0 + 0) * 768 + j] = a0;
        gi_out[(size_t)(b0 + 1) * 768 + j] = a1;
    }
    // gh: K=256
    {
        float a0 = gru_bhh[j], a1 = a0;
        const float4* w  = (const float4*)(gru_Whh + (size_t)j * 256);
        const float4* x0 = (const float4*)hs[0];
        const float4* x1 = (const float4*)hs[1];
        #pragma unroll 8
        for (int k = 0; k < 64; k++) {
            float4 wv = w[k], v0 = x0[k], v1 = x1[k];
            a0 += v0.x * wv.x + v0.y * wv.y + v0.z * wv.z + v0.w * wv.w;
            a1 += v1.x * wv.x + v1.y * wv.y + v1.z * wv.z + v1.w * wv.w;
        }
        gh_out[(size_t)(b0 + 0) * 768 + j] = a0;
        gh_out[(size_t)(b0 + 1) * 768 + j] = a1;
    }
}

// ---------------------------------------------------------------------------
// K1c: GRU gates + q = attn_h @ attn_W.T.   grid=128, block=256
// ---------------------------------------------------------------------------
__global__ __launch_bounds__(256) void k1c_gates_q(
    const float* __restrict__ gi, const float* __restrict__ gh,
    const float* __restrict__ attn_hidden, const float* __restrict__ attn_W,
    float* __restrict__ attn_h_out, float* __restrict__ q_out)
{
    const int b = blockIdx.x, t = threadIdx.x;
    __shared__ __align__(16) float ahn[256];

    {
        float hp = attn_hidden[b * 256 + t];
        float rg = sigmoidf_(gi[(size_t)b * 768 + t]       + gh[(size_t)b * 768 + t]);
        float zg = sigmoidf_(gi[(size_t)b * 768 + 256 + t] + gh[(size_t)b * 768 + 256 + t]);
        float ng = tanhf_(gi[(size_t)b * 768 + 512 + t] + rg * gh[(size_t)b * 768 + 512 + t]);
        float h  = (1.f - zg) * ng + zg * hp;
        ahn[t] = h;
        attn_h_out[b * 256 + t] = h;
    }
    __syncthreads();

    {
        float a = 0.f;
        const float4* w  = (const float4*)(attn_W + (size_t)t * 256);
        const float4* xv = (const float4*)ahn;
        #pragma unroll 8
        for (int k = 0; k < 64; k++) {
            float4 wv = w[k], v = xv[k];
            a += v.x * wv.x + v.y * wv.y + v.z * wv.z + v.w * wv.w;
        }
        q_out[b * 256 + t] = a;
    }
}

// ---------------------------------------------------------------------------
// KA: fused attention (R4 structure, full 256-col stage 1).
// L3-steering: stage-3 enc loads are NON-TEMPORAL (no L3 allocate) so encp
// (134 MB) stays L3-resident across graph replays; stage-1 reads then hit L3
// while stage-3 streams from HBM.
// grid = B*16 chunks of 64 t, block=256 (4 waves).
// ---------------------------------------------------------------------------
__global__ __launch_bounds__(256, 4) void ka_attn(
    const float* __restrict__ enc_proj, const float* __restrict__ enc,
    const float* __restrict__ q, const float* __restrict__ v,
    float* __restrict__ u_out, float* __restrict__ ctx_part,
    float* __restrict__ m_part, float* __restrict__ s_part)
{
    const int b     = blockIdx.x >> 4;
    const int chunk = blockIdx.x & 15;
    const int tid   = threadIdx.x;
    const int lane  = tid & 63;
    const int wv    = tid >> 6;    // 0..3
    const int g     = lane >> 4;   // 16-lane group 0..3
    const int gl    = lane & 15;

    __shared__ float ul[64];
    __shared__ float el[64];
    __shared__ __align__(16) float4 red[4][64];

    const int t0 = chunk * 64;

    // per-lane copies of q,v covering all 4 d-chunks of 64
    float4 qv[4], vv[4];
    #pragma unroll
    for (int c = 0; c < 4; c++) {
        qv[c] = ((const float4*)(q + b * 256))[c * 16 + gl];
        vv[c] = ((const float4*)v)[c * 16 + gl];
    }

    // ---- stage 1: u for 64 t's (16-lane group owns one t per pass) ----
    const float* ebase = enc_proj + ((size_t)(b * T_ + t0)) * 256;
    #pragma unroll
    for (int pass = 0; pass < 4; pass++) {
        const int t = wv * 16 + pass * 4 + g;
        const float4* row = (const float4*)(ebase + (size_t)t * 256);
        float s = 0.f;
        #pragma unroll
        for (int c = 0; c < 4; c++) {
            float4 pj = row[c * 16 + gl];
            s += tanh_fast(pj.x + qv[c].x) * vv[c].x
               + tanh_fast(pj.y + qv[c].y) * vv[c].y
               + tanh_fast(pj.z + qv[c].z) * vv[c].z
               + tanh_fast(pj.w + qv[c].w) * vv[c].w;
        }
        s += __shfl_xor(s, 1, 64);
        s += __shfl_xor(s, 2, 64);
        s += __shfl_xor(s, 4, 64);
        s += __shfl_xor(s, 8, 64);
        if (gl == 0) ul[t] = s;
    }
    __syncthreads();

    // ---- stage 2 (wave 0 only): chunk-local max / exp / sum ----
    if (wv == 0) {
        float x = ul[lane];
        u_out[b * T_ + t0 + lane] = x;
        float mx = waveReduceMax(x);
        float e = __expf(x - mx);
        el[lane] = e;
        float ss = waveReduceSum(e);
        if (lane == 0) {
            m_part[b * 16 + chunk] = mx;
            s_part[b * 16 + chunk] = ss;
        }
    }
    __syncthreads();

    // ---- stage 3: context partial over wave's 16 rows (nt stream) ----
    const float4* base2 = (const float4*)(enc + ((size_t)(b * T_ + t0)) * 256);
    float4 acc0 = {0.f, 0.f, 0.f, 0.f}, acc1 = {0.f, 0.f, 0.f, 0.f};
    #pragma unroll
    for (int i = 0; i < 16; i += 2) {
        int t = wv * 16 + i;
        float e0 = el[t], e1 = el[t + 1];
        float4 v0 = nt_load4(&base2[(size_t)t * 64 + lane]);
        float4 v1 = nt_load4(&base2[(size_t)(t + 1) * 64 + lane]);
        acc0.x += e0 * v0.x; acc0.y += e0 * v0.y; acc0.z += e0 * v0.z; acc0.w += e0 * v0.w;
        acc1.x += e1 * v1.x; acc1.y += e1 * v1.y; acc1.z += e1 * v1.z; acc1.w += e1 * v1.w;
    }
    acc0.x += acc1.x; acc0.y += acc1.y; acc0.z += acc1.z; acc0.w += acc1.w;
    red[wv][lane] = acc0;
    __syncthreads();
    if (tid < 64) {
        float4 s = red[0][tid];
        float4 a1 = red[1][tid], a2 = red[2][tid], a3 = red[3][tid];
        s.x += a1.x + a2.x + a3.x;
        s.y += a1.y + a2.y + a3.y;
        s.z += a1.z + a2.z + a3.z;
        s.w += a1.w + a2.w + a3.w;
        ((float4*)ctx_part)[(size_t)(b * 16 + chunk) * 64 + tid] = s;
    }
}

// ---------------------------------------------------------------------------
// KB: combine 16 partials -> context, scores, concat1.  grid=128 (per batch)
// ---------------------------------------------------------------------------
__global__ __launch_bounds__(256) void kb_combine(
    const float* __restrict__ u, const float* __restrict__ m_part,
    const float* __restrict__ s_part, const float* __restrict__ ctx_part,
    const float* __restrict__ attn_h,
    float* __restrict__ scores_out, float* __restrict__ ctx_out,
    float* __restrict__ concat1)
{
    const int b = blockIdx.x, tid = threadIdx.x;
    __shared__ float msh[16], ssh[16];
    if (tid < 16) {
        msh[tid] = m_part[b * 16 + tid];
        ssh[tid] = s_part[b * 16 + tid];
    }
    __syncthreads();

    float M = msh[0];
    #pragma unroll
    for (int c = 1; c < 16; c++) M = fmaxf(M, msh[c]);
    float S = 0.f;
    #pragma unroll
    for (int c = 0; c < 16; c++) S += ssh[c] * __expf(msh[c] - M);
    float invS = 1.f / S;

    {
        float a = 0.f;
        #pragma unroll
        for (int c = 0; c < 16; c++)
            a += ctx_part[(size_t)(b * 16 + c) * 256 + tid] * __expf(msh[c] - M);
        a *= invS;
        ctx_out[b * 256 + tid] = a;
        concat1[b * 512 + tid] = a;
        concat1[b * 512 + 256 + tid] = attn_h[b * 256 + tid];
    }

    #pragma unroll
    for (int i = 0; i < 4; i++) {
        int t = i * 256 + tid;
        scores_out[b * T_ + t] = __expf(u[b * T_ + t] - M) * invS;
    }
}

// ---------------------------------------------------------------------------
// GEMM: part[z][m][n] = A_seg[m][k0:k0+KSZ] @ W_seg[n][k0:k0+KSZ]^T
// grid = (N/64, 2, nseg*ksPerSeg)
// ---------------------------------------------------------------------------
__global__ __launch_bounds__(256) void gemm512_splitk(
    const float* __restrict__ A1, const float* __restrict__ W1,
    const float* __restrict__ A2, const float* __restrict__ W2,
    float* __restrict__ part, int N, int ksPerSeg)
{
    const int n0 = blockIdx.x * 64, m0 = blockIdx.y * 64;
    const int seg = blockIdx.z / ksPerSeg, ls = blockIdx.z % ksPerSeg;
    const int KSZ = 512 / ksPerSeg;
    const float* A = seg ? A2 : A1;
    const float* W = seg ? W2 : W1;
    const int k0 = ls * KSZ;

    __shared__ __align__(16) float As[32][68];
    __shared__ __align__(16) float Ws[32][68];

    const int tid = threadIdx.x;
    const int tm = tid & 15, tn = tid >> 4;
    const int rs = tid >> 3, qs = tid & 7;

    float acc[4][4] = {};

    for (int kt = 0; kt < KSZ; kt += 32) {
        #pragma unroll
        for (int it = 0; it < 2; it++) {
            int r = rs + it * 32;
            float4 av = *(const float4*)(A + (size_t)(m0 + r) * 512 + k0 + kt + qs * 4);
            As[qs * 4 + 0][r] = av.x; As[qs * 4 + 1][r] = av.y;
            As[qs * 4 + 2][r] = av.z; As[qs * 4 + 3][r] = av.w;
            float4 wv = *(const float4*)(W + (size_t)(n0 + r) * 512 + k0 + kt + qs * 4);
            Ws[qs * 4 + 0][r] = wv.x; Ws[qs * 4 + 1][r] = wv.y;
            Ws[qs * 4 + 2][r] = wv.z; Ws[qs * 4 + 3][r] = wv.w;
        }
        __syncthreads();
        #pragma unroll
        for (int kk = 0; kk < 32; kk++) {
            float4 a = *(const float4*)&As[kk][tm * 4];
            float4 w = *(const float4*)&Ws[kk][tn * 4];
            acc[0][0] += a.x * w.x; acc[0][1] += a.x * w.y; acc[0][2] += a.x * w.z; acc[0][3] += a.x * w.w;
            acc[1][0] += a.y * w.x; acc[1][1] += a.y * w.y; acc[1][2] += a.y * w.z; acc[1][3] += a.y * w.w;
            acc[2][0] += a.z * w.x; acc[2][1] += a.z * w.y; acc[2][2] += a.z * w.z; acc[2][3] += a.z * w.w;
            acc[3][0] += a.w * w.x; acc[3][1] += a.w * w.y; acc[3][2] += a.w * w.z; acc[3][3] += a.w * w.w;
        }
        __syncthreads();
    }

    float* pb = part + ((size_t)blockIdx.z * 128 + m0) * N + n0;
    #pragma unroll
    for (int i = 0; i < 4; i++) {
        float4 o = {acc[i][0], acc[i][1], acc[i][2], acc[i][3]};
        *(float4*)(pb + (size_t)(tm * 4 + i) * N + tn * 4) = o;
    }
}

// ---------------------------------------------------------------------------
// E_rnn: x = sum_z part[z] + bias     (N=512, 16 slices)
// ---------------------------------------------------------------------------
__global__ __launch_bounds__(256) void e_rnn(
    const float* __restrict__ part, const float* __restrict__ bias,
    float* __restrict__ x)
{
    const int idx = blockIdx.x * 256 + threadIdx.x;
    const int n = idx & 511;
    float a = bias[n];
    #pragma unroll
    for (int z = 0; z < 16; z++) a += part[(size_t)z * 65536 + idx];
    x[idx] = a;
}

// ---------------------------------------------------------------------------
// E_lstm: gate reduce (16 slices, N=2048) + LSTM cell + x_new = x_prev + h
// ---------------------------------------------------------------------------
__global__ __launch_bounds__(256) void e_lstm(
    const float* __restrict__ part,
    const float* __restrict__ bih, const float* __restrict__ bhh,
    const float* __restrict__ c_prev, const float* __restrict__ x_prev,
    float* __restrict__ h_out, float* __restrict__ c_out, float* __restrict__ x_new)
{
    const int idx = blockIdx.x * 256 + threadIdx.x;
    const int bb = idx >> 9, j = idx & 511;
    float gi = bih[j] + bhh[j];
    float gf = bih[512 + j] + bhh[512 + j];
    float gg = bih[1024 + j] + bhh[1024 + j];
    float go = bih[1536 + j] + bhh[1536 + j];
    #pragma unroll
    for (int z = 0; z < 16; z++) {
        const float* p = part + ((size_t)z * 128 + bb) * 2048;
        gi += p[j]; gf += p[512 + j]; gg += p[1024 + j]; go += p[1536 + j];
    }
    float c = sigmoidf_(gf) * c_prev[idx] + sigmoidf_(gi) * tanhf_(gg);
    float h = sigmoidf_(go) * tanhf_(c);
    h_out[idx] = h;
    c_out[idx] = c;
    x_new[idx] = x_prev[idx] + h;
}

// ---------------------------------------------------------------------------
// E_lstm2 + mel: grid=128 (per batch), block=512. x3 stays in LDS.
// ---------------------------------------------------------------------------
__global__ __launch_bounds__(512) void e_lstm2_mel(
    const float* __restrict__ part,
    const float* __restrict__ bih, const float* __restrict__ bhh,
    const float* __restrict__ c_prev, const float* __restrict__ x_prev,
    const float* __restrict__ mel_W, const int* __restrict__ r_ptr,
    float* __restrict__ h_out, float* __restrict__ c_out,
    float* __restrict__ mels)
{
    const int b = blockIdx.x, j = threadIdx.x;
    __shared__ __align__(16) float xs[512];

    const int idx = b * 512 + j;
    float gi = bih[j] + bhh[j];
    float gf = bih[512 + j] + bhh[512 + j];
    float gg = bih[1024 + j] + bhh[1024 + j];
    float go = bih[1536 + j] + bhh[1536 + j];
    #pragma unroll
    for (int z = 0; z < 16; z++) {
        const float* p = part + ((size_t)z * 128 + b) * 2048;
        gi += p[j]; gf += p[512 + j]; gg += p[1024 + j]; go += p[1536 + j];
    }
    float c = sigmoidf_(gf) * c_prev[idx] + sigmoidf_(gi) * tanhf_(gg);
    float h = sigmoidf_(go) * tanhf_(c);
    h_out[idx] = h;
    c_out[idx] = c;
    xs[j] = x_prev[idx] + h;
    __syncthreads();

    const int r = r_ptr[0];
    const int tot = 80 * r;
    for (int n = j; n < tot; n += 512) {
        int m = n / r, rr = n % r;
        const float4* w  = (const float4*)(mel_W + (size_t)(m * 20 + rr) * 512);
        const float4* xv = (const float4*)xs;
        float a = 0.f;
        #pragma unroll 8
        for (int k = 0; k < 128; k++) {
            float4 wv = w[k], vv = xv[k];
            a += wv.x * vv.x + wv.y * vv.y + wv.z * vv.z + wv.w * vv.w;
        }
        mels[(size_t)b * tot + n] = a;
    }
}

// ---------------------------------------------------------------------------
extern "C" void kernel_launch(void* const* d_in, const int* in_sizes, int n_in,
                              void* d_out, int out_size, void* d_ws, size_t ws_size,
                              hipStream_t stream)
{
    const float* enc   = (const float*)d_in[0];
    const float* encp  = (const float*)d_in[1];
    const float* pre   = (const float*)d_in[2];
    const float* ah_in = (const float*)d_in[3];
    const float* r1h   = (const float*)d_in[4];
    const float* r2h   = (const float*)d_in[5];
    const float* r1c   = (const float*)d_in[6];
    const float* r2c   = (const float*)d_in[7];
    const float* cvec  = (const float*)d_in[8];
    const float* fc1W  = (const float*)d_in[9];
    const float* fc1b  = (const float*)d_in[10];
    const float* fc2W  = (const float*)d_in[11];
    const float* fc2b  = (const float*)d_in[12];
    const float* attnW = (const float*)d_in[13];
    const float* attnv = (const float*)d_in[14];
    const float* gWih  = (const float*)d_in[15];
    const float* gWhh  = (const float*)d_in[16];
    const float* gbih  = (const float*)d_in[17];
    const float* gbhh  = (const float*)d_in[18];
    const float* rinW  = (const float*)d_in[19];
    const float* rinb  = (const float*)d_in[20];
    const float* l1Wih = (const float*)d_in[21];
    const float* l1Whh = (const float*)d_in[22];
    const float* l1bih = (const float*)d_in[23];
    const float* l1bhh = (const float*)d_in[24];
    const float* l2Wih = (const float*)d_in[25];
    const float* l2Whh = (const float*)d_in[26];
    const float* l2bih = (const float*)d_in[27];
    const float* l2bhh = (const float*)d_in[28];
    const float* melW  = (const float*)d_in[29];
    const int*   rp    = (const int*)d_in[30];

    float* out = (float*)d_out;
    float* o_mels  = out + 0;        // 128*80*2
    float* o_scor  = out + 20480;    // 128*1024
    float* o_attnh = out + 151552;   // 128*256
    float* o_r1h   = out + 184320;   // 128*512
    float* o_r2h   = out + 249856;
    float* o_r1c   = out + 315392;
    float* o_r2c   = out + 380928;
    float* o_ctx   = out + 446464;   // 128*256

    float* ws     = (float*)d_ws;
    float* w_q    = ws + 0;          // 32768
    float* w_u    = ws + 32768;      // 131072
    float* w_m    = ws + 163840;     // 2048
    float* w_s    = ws + 165888;     // 2048
    float* w_ctxp = ws + 167936;     // 16*128*256 = 524288
    float* w_cat1 = ws + 692224;     // 65536
    float* w_x    = ws + 757760;     // 65536
    float* w_x2   = ws + 823296;     // 65536
    float* w_part = ws + 888832;     // 16*128*2048 = 4194304 max

    // front-end scratch reuses the w_part region (free until the GEMM phase)
    float* w_gi = w_part;            // 128*768
    float* w_gh = w_part + 98304;    // 128*768

    hipLaunchKernelGGL(k1b_fused, dim3(3, 64), dim3(256), 0, stream,
                       pre, cvec, ah_in, fc1W, fc1b, fc2W, fc2b,
                       gWih, gWhh, gbih, gbhh, w_gi, w_gh);

    hipLaunchKernelGGL(k1c_gates_q, dim3(128), dim3(256), 0, stream,
                       w_gi, w_gh, ah_in, attnW, o_attnh, w_q);

    hipLaunchKernelGGL(ka_attn, dim3(2048), dim3(256), 0, stream,
                       encp, enc, w_q, attnv, w_u, w_ctxp, w_m, w_s);

    hipLaunchKernelGGL(kb_combine, dim3(128), dim3(256), 0, stream,
                       w_u, w_m, w_s, w_ctxp, o_attnh, o_scor, o_ctx, w_cat1);

    // rnn_in: K=512, 16 k-slices -> 256 blocks
    hipLaunchKernelGGL(gemm512_splitk, dim3(8, 2, 16), dim3(256), 0, stream,
                       w_cat1, rinW, w_cat1, rinW, w_part, 512, 16);
    hipLaunchKernelGGL(e_rnn, dim3(256), dim3(256), 0, stream, w_part, rinb, w_x);

    // LSTM 1: 2 segments x 8 k-slices -> 1024 blocks (4/CU)
    hipLaunchKernelGGL(gemm512_splitk, dim3(32, 2, 16), dim3(256), 0, stream,
                       w_x, l1Wih, r1h, l1Whh, w_part, 2048, 8);
    hipLaunchKernelGGL(e_lstm, dim3(256), dim3(256), 0, stream,
                       w_part, l1bih, l1bhh, r1c, w_x, o_r1h, o_r1c, w_x2);

    // LSTM 2 + mel
    hipLaunchKernelGGL(gemm512_splitk, dim3(32, 2, 16), dim3(256), 0, stream,
                       w_x2, l2Wih, r2h, l2Whh, w_part, 2048, 8);
    hipLaunchKernelGGL(e_lstm2_mel, dim3(128), dim3(512), 0, stream,
                       w_part, l2bih, l2bhh, r2c, w_x2, melW, rp,
                       o_r2h, o_r2c, o_mels);
}

// Round 12
// 144.026 us; speedup vs baseline: 1.0246x; 1.0003x over previous
//
#include <hip/hip_runtime.h>
#include <math.h>

#define B_   128
#define T_   1024
#define D_   256
#define L_   512

__device__ __forceinline__ float sigmoidf_(float x) {
    return 1.f / (1.f + __expf(-x));
}
__device__ __forceinline__ float tanhf_(float x) {
    x = fminf(fmaxf(x, -15.f), 15.f);
    float e = __expf(2.f * x);
    return (e - 1.f) / (e + 1.f);
}
// tanh(x) = 1 - 2/(exp(2x)+1); exact identity, v_exp + v_rcp
__device__ __forceinline__ float tanh_fast(float x) {
    float e = __expf(2.f * x);
    return 1.f - 2.f * __builtin_amdgcn_rcpf(e + 1.f);
}
__device__ __forceinline__ float waveReduceSum(float v) {
    #pragma unroll
    for (int o = 32; o > 0; o >>= 1) v += __shfl_xor(v, o, 64);
    return v;
}
__device__ __forceinline__ float waveReduceMax(float v) {
    #pragma unroll
    for (int o = 32; o > 0; o >>= 1) v = fmaxf(v, __shfl_xor(v, o, 64));
    return v;
}

// non-temporal float4 load: no-L3-allocate stream (protects the other
// stream's residency)
typedef float f4v __attribute__((ext_vector_type(4)));
__device__ __forceinline__ float4 nt_load4(const float4* p) {
    f4v v = __builtin_nontemporal_load((const f4v*)p);
    return make_float4(v.x, v.y, v.z, v.w);
}

// ---------------------------------------------------------------------------
// K1b fused: prenet (recomputed per block, cheap) + GRU gate GEMVs.
// grid = (3 j-tiles, 64 batch-pairs), block = 256.
// ---------------------------------------------------------------------------
__global__ __launch_bounds__(256) void k1b_fused(
    const float* __restrict__ prenet_in, const float* __restrict__ context_vec,
    const float* __restrict__ attn_hidden,
    const float* __restrict__ fc1_W, const float* __restrict__ fc1_b,
    const float* __restrict__ fc2_W, const float* __restrict__ fc2_b,
    const float* __restrict__ gru_Wih, const float* __restrict__ gru_Whh,
    const float* __restrict__ gru_bih, const float* __restrict__ gru_bhh,
    float* __restrict__ gi_out, float* __restrict__ gh_out)
{
    const int t = threadIdx.x;
    const int j = blockIdx.x * 256 + t;
    const int b0 = blockIdx.y * 2;

    __shared__ __align__(16) float pin[2][80];
    __shared__ __align__(16) float p1[2][256];
    __shared__ __align__(16) float xs[2][384];   // [cvec | prenet_out]
    __shared__ __align__(16) float hs[2][256];

    if (t < 160) pin[t / 80][t % 80] = prenet_in[(b0 + t / 80) * 80 + (t % 80)];
    xs[0][t] = context_vec[b0 * 256 + t];
    xs[1][t] = context_vec[(b0 + 1) * 256 + t];
    hs[0][t] = attn_hidden[b0 * 256 + t];
    hs[1][t] = attn_hidden[(b0 + 1) * 256 + t];
    __syncthreads();

    // fc1: 256 outputs x 2 batches, K=80
    {
        float a0 = fc1_b[t], a1 = a0;
        const float4* w  = (const float4*)(fc1_W + t * 80);
        const float4* x0 = (const float4*)pin[0];
        const float4* x1 = (const float4*)pin[1];
        #pragma unroll
        for (int k = 0; k < 20; k++) {
            float4 wv = w[k], v0 = x0[k], v1 = x1[k];
            a0 += v0.x * wv.x + v0.y * wv.y + v0.z * wv.z + v0.w * wv.w;
            a1 += v1.x * wv.x + v1.y * wv.y + v1.z * wv.z + v1.w * wv.w;
        }
        p1[0][t] = fmaxf(a0, 0.f);
        p1[1][t] = fmaxf(a1, 0.f);
    }
    __syncthreads();

    // fc2: 128 outputs x 2 batches, K=256 (t<128 -> batch0, t>=128 -> batch1)
    {
        const int bb = t >> 7, jj = t & 127;
        float a = fc2_b[jj];
        const float4* w  = (const float4*)(fc2_W + jj * 256);
        const float4* xv = (const float4*)p1[bb];
        #pragma unroll 8
        for (int k = 0; k < 64; k++) {
            float4 wv = w[k], v = xv[k];
            a += v.x * wv.x + v.y * wv.y + v.z * wv.z + v.w * wv.w;
        }
        xs[bb][256 + jj] = fmaxf(a, 0.f);
    }
    __syncthreads();

    // gi: K=384
    {
        float a0 = gru_bih[j], a1 = a0;
        const float4* w  = (const float4*)(gru_Wih + (size_t)j * 384);
        const float4* x0 = (const float4*)xs[0];
        const float4* x1 = (const float4*)xs[1];
        #pragma unroll 8
        for (int k = 0; k < 96; k++) {
            float4 wv = w[k], v0 = x0[k], v1 = x1[k];
            a0 += v0.x * wv.x + v0.y * wv.y + v0.z * wv.z + v0.w * wv.w;
            a1 += v1.x * wv.x + v1.y * wv.y + v1.z * wv.z + v1.w * wv.w;
        }
        gi_out[(size_t)(b0 + 0) * 768 + j] = a0;
        gi_out[(size_t)(b0 + 1) * 768 + j] = a1;
    }
    // gh: K=256
    {
        float a0 = gru_bhh[j], a1 = a0;
        const float4* w  = (const float4*)(gru_Whh + (size_t)j * 256);
        const float4* x0 = (const float4*)hs[0];
        const float4* x1 = (const float4*)hs[1];
        #pragma unroll 8
        for (int k = 0; k < 64; k++) {
            float4 wv = w[k], v0 = x0[k], v1 = x1[k];
            a0 += v0.x * wv.x + v0.y * wv.y + v0.z * wv.z + v0.w * wv.w;
            a1 += v1.x * wv.x + v1.y * wv.y + v1.z * wv.z + v1.w * wv.w;
        }
        gh_out[(size_t)(b0 + 0) * 768 + j] = a0;
        gh_out[(size_t)(b0 + 1) * 768 + j] = a1;
    }
}

// ---------------------------------------------------------------------------
// K1c: GRU gates + q = attn_h @ attn_W.T.   grid=128, block=256
// ---------------------------------------------------------------------------
__global__ __launch_bounds__(256) void k1c_gates_q(
    const float* __restrict__ gi, const float* __restrict__ gh,
    const float* __restrict__ attn_hidden, const float* __restrict__ attn_W,
    float* __restrict__ attn_h_out, float* __restrict__ q_out)
{
    const int b = blockIdx.x, t = threadIdx.x;
    __shared__ __align__(16) float ahn[256];

    {
        float hp = attn_hidden[b * 256 + t];
        float rg = sigmoidf_(gi[(size_t)b * 768 + t]       + gh[(size_t)b * 768 + t]);
        float zg = sigmoidf_(gi[(size_t)b * 768 + 256 + t] + gh[(size_t)b * 768 + 256 + t]);
        float ng = tanhf_(gi[(size_t)b * 768 + 512 + t] + rg * gh[(size_t)b * 768 + 512 + t]);
        float h  = (1.f - zg) * ng + zg * hp;
        ahn[t] = h;
        attn_h_out[b * 256 + t] = h;
    }
    __syncthreads();

    {
        float a = 0.f;
        const float4* w  = (const float4*)(attn_W + (size_t)t * 256);
        const float4* xv = (const float4*)ahn;
        #pragma unroll 8
        for (int k = 0; k < 64; k++) {
            float4 wv = w[k], v = xv[k];
            a += v.x * wv.x + v.y * wv.y + v.z * wv.z + v.w * wv.w;
        }
        q_out[b * 256 + t] = a;
    }
}

// ---------------------------------------------------------------------------
// KA: fused attention.  L3-steering (nt on enc only) + WIDE stage-3 load
// window: all 16 rows loaded into an explicit register buffer before the
// FMA pass, so 16 nt loads stay in flight per wave (16KB/wave).
// grid = B*16 chunks of 64 t, block=256 (4 waves).
// ---------------------------------------------------------------------------
__global__ __launch_bounds__(256, 4) void ka_attn(
    const float* __restrict__ enc_proj, const float* __restrict__ enc,
    const float* __restrict__ q, const float* __restrict__ v,
    float* __restrict__ u_out, float* __restrict__ ctx_part,
    float* __restrict__ m_part, float* __restrict__ s_part)
{
    const int b     = blockIdx.x >> 4;
    const int chunk = blockIdx.x & 15;
    const int tid   = threadIdx.x;
    const int lane  = tid & 63;
    const int wv    = tid >> 6;    // 0..3
    const int g     = lane >> 4;   // 16-lane group 0..3
    const int gl    = lane & 15;

    __shared__ float ul[64];
    __shared__ float el[64];
    __shared__ __align__(16) float4 red[4][64];

    const int t0 = chunk * 64;

    // per-lane copies of q,v covering all 4 d-chunks of 64
    float4 qv[4], vv[4];
    #pragma unroll
    for (int c = 0; c < 4; c++) {
        qv[c] = ((const float4*)(q + b * 256))[c * 16 + gl];
        vv[c] = ((const float4*)v)[c * 16 + gl];
    }

    // ---- stage 1: u for 64 t's (16-lane group owns one t per pass) ----
    // encp reads are normal (L3-resident after first replay).
    const float* ebase = enc_proj + ((size_t)(b * T_ + t0)) * 256;
    #pragma unroll
    for (int pass = 0; pass < 4; pass++) {
        const int t = wv * 16 + pass * 4 + g;
        const float4* row = (const float4*)(ebase + (size_t)t * 256);
        float s = 0.f;
        #pragma unroll
        for (int c = 0; c < 4; c++) {
            float4 pj = row[c * 16 + gl];
            s += tanh_fast(pj.x + qv[c].x) * vv[c].x
               + tanh_fast(pj.y + qv[c].y) * vv[c].y
               + tanh_fast(pj.z + qv[c].z) * vv[c].z
               + tanh_fast(pj.w + qv[c].w) * vv[c].w;
        }
        s += __shfl_xor(s, 1, 64);
        s += __shfl_xor(s, 2, 64);
        s += __shfl_xor(s, 4, 64);
        s += __shfl_xor(s, 8, 64);
        if (gl == 0) ul[t] = s;
    }
    __syncthreads();

    // ---- stage 2 (wave 0 only): chunk-local max / exp / sum ----
    if (wv == 0) {
        float x = ul[lane];
        u_out[b * T_ + t0 + lane] = x;
        float mx = waveReduceMax(x);
        float e = __expf(x - mx);
        el[lane] = e;
        float ss = waveReduceSum(e);
        if (lane == 0) {
            m_part[b * 16 + chunk] = mx;
            s_part[b * 16 + chunk] = ss;
        }
    }
    __syncthreads();

    // ---- stage 3: wide-window nt stream of the wave's 16 enc rows ----
    const float4* base2 = (const float4*)(enc + ((size_t)(b * T_ + t0)) * 256);
    float4 vbuf[16];
    #pragma unroll
    for (int i = 0; i < 16; i++)
        vbuf[i] = nt_load4(&base2[(size_t)(wv * 16 + i) * 64 + lane]);

    float4 acc0 = {0.f, 0.f, 0.f, 0.f}, acc1 = {0.f, 0.f, 0.f, 0.f};
    #pragma unroll
    for (int i = 0; i < 16; i += 2) {
        float e0 = el[wv * 16 + i], e1 = el[wv * 16 + i + 1];
        acc0.x += e0 * vbuf[i].x;     acc0.y += e0 * vbuf[i].y;
        acc0.z += e0 * vbuf[i].z;     acc0.w += e0 * vbuf[i].w;
        acc1.x += e1 * vbuf[i + 1].x; acc1.y += e1 * vbuf[i + 1].y;
        acc1.z += e1 * vbuf[i + 1].z; acc1.w += e1 * vbuf[i + 1].w;
    }
    acc0.x += acc1.x; acc0.y += acc1.y; acc0.z += acc1.z; acc0.w += acc1.w;
    red[wv][lane] = acc0;
    __syncthreads();
    if (tid < 64) {
        float4 s = red[0][tid];
        float4 a1 = red[1][tid], a2 = red[2][tid], a3 = red[3][tid];
        s.x += a1.x + a2.x + a3.x;
        s.y += a1.y + a2.y + a3.y;
        s.z += a1.z + a2.z + a3.z;
        s.w += a1.w + a2.w + a3.w;
        ((float4*)ctx_part)[(size_t)(b * 16 + chunk) * 64 + tid] = s;
    }
}

// ---------------------------------------------------------------------------
// KB: combine 16 partials -> context, scores, concat1.  grid=128 (per batch)
// ---------------------------------------------------------------------------
__global__ __launch_bounds__(256) void kb_combine(
    const float* __restrict__ u, const float* __restrict__ m_part,
    const float* __restrict__ s_part, const float* __restrict__ ctx_part,
    const float* __restrict__ attn_h,
    float* __restrict__ scores_out, float* __restrict__ ctx_out,
    float* __restrict__ concat1)
{
    const int b = blockIdx.x, tid = threadIdx.x;
    __shared__ float msh[16], ssh[16];
    if (tid < 16) {
        msh[tid] = m_part[b * 16 + tid];
        ssh[tid] = s_part[b * 16 + tid];
    }
    __syncthreads();

    float M = msh[0];
    #pragma unroll
    for (int c = 1; c < 16; c++) M = fmaxf(M, msh[c]);
    float S = 0.f;
    #pragma unroll
    for (int c = 0; c < 16; c++) S += ssh[c] * __expf(msh[c] - M);
    float invS = 1.f / S;

    {
        float a = 0.f;
        #pragma unroll
        for (int c = 0; c < 16; c++)
            a += ctx_part[(size_t)(b * 16 + c) * 256 + tid] * __expf(msh[c] - M);
        a *= invS;
        ctx_out[b * 256 + tid] = a;
        concat1[b * 512 + tid] = a;
        concat1[b * 512 + 256 + tid] = attn_h[b * 256 + tid];
    }

    #pragma unroll
    for (int i = 0; i < 4; i++) {
        int t = i * 256 + tid;
        scores_out[b * T_ + t] = __expf(u[b * T_ + t] - M) * invS;
    }
}

// ---------------------------------------------------------------------------
// GEMM: part[z][m][n] = A_seg[m][k0:k0+KSZ] @ W_seg[n][k0:k0+KSZ]^T
// grid = (N/64, 2, nseg*ksPerSeg)
// ---------------------------------------------------------------------------
__global__ __launch_bounds__(256) void gemm512_splitk(
    const float* __restrict__ A1, const float* __restrict__ W1,
    const float* __restrict__ A2, const float* __restrict__ W2,
    float* __restrict__ part, int N, int ksPerSeg)
{
    const int n0 = blockIdx.x * 64, m0 = blockIdx.y * 64;
    const int seg = blockIdx.z / ksPerSeg, ls = blockIdx.z % ksPerSeg;
    const int KSZ = 512 / ksPerSeg;
    const float* A = seg ? A2 : A1;
    const float* W = seg ? W2 : W1;
    const int k0 = ls * KSZ;

    __shared__ __align__(16) float As[32][68];
    __shared__ __align__(16) float Ws[32][68];

    const int tid = threadIdx.x;
    const int tm = tid & 15, tn = tid >> 4;
    const int rs = tid >> 3, qs = tid & 7;

    float acc[4][4] = {};

    for (int kt = 0; kt < KSZ; kt += 32) {
        #pragma unroll
        for (int it = 0; it < 2; it++) {
            int r = rs + it * 32;
            float4 av = *(const float4*)(A + (size_t)(m0 + r) * 512 + k0 + kt + qs * 4);
            As[qs * 4 + 0][r] = av.x; As[qs * 4 + 1][r] = av.y;
            As[qs * 4 + 2][r] = av.z; As[qs * 4 + 3][r] = av.w;
            float4 wv = *(const float4*)(W + (size_t)(n0 + r) * 512 + k0 + kt + qs * 4);
            Ws[qs * 4 + 0][r] = wv.x; Ws[qs * 4 + 1][r] = wv.y;
            Ws[qs * 4 + 2][r] = wv.z; Ws[qs * 4 + 3][r] = wv.w;
        }
        __syncthreads();
        #pragma unroll
        for (int kk = 0; kk < 32; kk++) {
            float4 a = *(const float4*)&As[kk][tm * 4];
            float4 w = *(const float4*)&Ws[kk][tn * 4];
            acc[0][0] += a.x * w.x; acc[0][1] += a.x * w.y; acc[0][2] += a.x * w.z; acc[0][3] += a.x * w.w;
            acc[1][0] += a.y * w.x; acc[1][1] += a.y * w.y; acc[1][2] += a.y * w.z; acc[1][3] += a.y * w.w;
            acc[2][0] += a.z * w.x; acc[2][1] += a.z * w.y; acc[2][2] += a.z * w.z; acc[2][3] += a.z * w.w;
            acc[3][0] += a.w * w.x; acc[3][1] += a.w * w.y; acc[3][2] += a.w * w.z; acc[3][3] += a.w * w.w;
        }
        __syncthreads();
    }

    float* pb = part + ((size_t)blockIdx.z * 128 + m0) * N + n0;
    #pragma unroll
    for (int i = 0; i < 4; i++) {
        float4 o = {acc[i][0], acc[i][1], acc[i][2], acc[i][3]};
        *(float4*)(pb + (size_t)(tm * 4 + i) * N + tn * 4) = o;
    }
}

// ---------------------------------------------------------------------------
// E_rnn: x = sum_z part[z] + bias     (N=512, 16 slices)
// ---------------------------------------------------------------------------
__global__ __launch_bounds__(256) void e_rnn(
    const float* __restrict__ part, const float* __restrict__ bias,
    float* __restrict__ x)
{
    const int idx = blockIdx.x * 256 + threadIdx.x;
    const int n = idx & 511;
    float a = bias[n];
    #pragma unroll
    for (int z = 0; z < 16; z++) a += part[(size_t)z * 65536 + idx];
    x[idx] = a;
}

// ---------------------------------------------------------------------------
// E_lstm: gate reduce (16 slices, N=2048) + LSTM cell + x_new = x_prev + h
// ---------------------------------------------------------------------------
__global__ __launch_bounds__(256) void e_lstm(
    const float* __restrict__ part,
    const float* __restrict__ bih, const float* __restrict__ bhh,
    const float* __restrict__ c_prev, const float* __restrict__ x_prev,
    float* __restrict__ h_out, float* __restrict__ c_out, float* __restrict__ x_new)
{
    const int idx = blockIdx.x * 256 + threadIdx.x;
    const int bb = idx >> 9, j = idx & 511;
    float gi = bih[j] + bhh[j];
    float gf = bih[512 + j] + bhh[512 + j];
    float gg = bih[1024 + j] + bhh[1024 + j];
    float go = bih[1536 + j] + bhh[1536 + j];
    #pragma unroll
    for (int z = 0; z < 16; z++) {
        const float* p = part + ((size_t)z * 128 + bb) * 2048;
        gi += p[j]; gf += p[512 + j]; gg += p[1024 + j]; go += p[1536 + j];
    }
    float c = sigmoidf_(gf) * c_prev[idx] + sigmoidf_(gi) * tanhf_(gg);
    float h = sigmoidf_(go) * tanhf_(c);
    h_out[idx] = h;
    c_out[idx] = c;
    x_new[idx] = x_prev[idx] + h;
}

// ---------------------------------------------------------------------------
// E_lstm2 + mel: grid=128 (per batch), block=512. x3 stays in LDS.
// ---------------------------------------------------------------------------
__global__ __launch_bounds__(512) void e_lstm2_mel(
    const float* __restrict__ part,
    const float* __restrict__ bih, const float* __restrict__ bhh,
    const float* __restrict__ c_prev, const float* __restrict__ x_prev,
    const float* __restrict__ mel_W, const int* __restrict__ r_ptr,
    float* __restrict__ h_out, float* __restrict__ c_out,
    float* __restrict__ mels)
{
    const int b = blockIdx.x, j = threadIdx.x;
    __shared__ __align__(16) float xs[512];

    const int idx = b * 512 + j;
    float gi = bih[j] + bhh[j];
    float gf = bih[512 + j] + bhh[512 + j];
    float gg = bih[1024 + j] + bhh[1024 + j];
    float go = bih[1536 + j] + bhh[1536 + j];
    #pragma unroll
    for (int z = 0; z < 16; z++) {
        const float* p = part + ((size_t)z * 128 + b) * 2048;
        gi += p[j]; gf += p[512 + j]; gg += p[1024 + j]; go += p[1536 + j];
    }
    float c = sigmoidf_(gf) * c_prev[idx] + sigmoidf_(gi) * tanhf_(gg);
    float h = sigmoidf_(go) * tanhf_(c);
    h_out[idx] = h;
    c_out[idx] = c;
    xs[j] = x_prev[idx] + h;
    __syncthreads();

    const int r = r_ptr[0];
    const int tot = 80 * r;
    for (int n = j; n < tot; n += 512) {
        int m = n / r, rr = n % r;
        const float4* w  = (const float4*)(mel_W + (size_t)(m * 20 + rr) * 512);
        const float4* xv = (const float4*)xs;
        float a = 0.f;
        #pragma unroll 8
        for (int k = 0; k < 128; k++) {
            float4 wv = w[k], vv = xv[k];
            a += wv.x * vv.x + wv.y * vv.y + wv.z * vv.z + wv.w * vv.w;
        }
        mels[(size_t)b * tot + n] = a;
    }
}

// ---------------------------------------------------------------------------
extern "C" void kernel_launch(void* const* d_in, const int* in_sizes, int n_in,
                              void* d_out, int out_size, void* d_ws, size_t ws_size,
                              hipStream_t stream)
{
    const float* enc   = (const float*)d_in[0];
    const float* encp  = (const float*)d_in[1];
    const float* pre   = (const float*)d_in[2];
    const float* ah_in = (const float*)d_in[3];
    const float* r1h   = (const float*)d_in[4];
    const float* r2h   = (const float*)d_in[5];
    const float* r1c   = (const float*)d_in[6];
    const float* r2c   = (const float*)d_in[7];
    const float* cvec  = (const float*)d_in[8];
    const float* fc1W  = (const float*)d_in[9];
    const float* fc1b  = (const float*)d_in[10];
    const float* fc2W  = (const float*)d_in[11];
    const float* fc2b  = (const float*)d_in[12];
    const float* attnW = (const float*)d_in[13];
    const float* attnv = (const float*)d_in[14];
    const float* gWih  = (const float*)d_in[15];
    const float* gWhh  = (const float*)d_in[16];
    const float* gbih  = (const float*)d_in[17];
    const float* gbhh  = (const float*)d_in[18];
    const float* rinW  = (const float*)d_in[19];
    const float* rinb  = (const float*)d_in[20];
    const float* l1Wih = (const float*)d_in[21];
    const float* l1Whh = (const float*)d_in[22];
    const float* l1bih = (const float*)d_in[23];
    const float* l1bhh = (const float*)d_in[24];
    const float* l2Wih = (const float*)d_in[25];
    const float* l2Whh = (const float*)d_in[26];
    const float* l2bih = (const float*)d_in[27];
    const float* l2bhh = (const float*)d_in[28];
    const float* melW  = (const float*)d_in[29];
    const int*   rp    = (const int*)d_in[30];

    float* out = (float*)d_out;
    float* o_mels  = out + 0;        // 128*80*2
    float* o_scor  = out + 20480;    // 128*1024
    float* o_attnh = out + 151552;   // 128*256
    float* o_r1h   = out + 184320;   // 128*512
    float* o_r2h   = out + 249856;
    float* o_r1c   = out + 315392;
    float* o_r2c   = out + 380928;
    float* o_ctx   = out + 446464;   // 128*256

    float* ws     = (float*)d_ws;
    float* w_q    = ws + 0;          // 32768
    float* w_u    = ws + 32768;      // 131072
    float* w_m    = ws + 163840;     // 2048
    float* w_s    = ws + 165888;     // 2048
    float* w_ctxp = ws + 167936;     // 16*128*256 = 524288
    float* w_cat1 = ws + 692224;     // 65536
    float* w_x    = ws + 757760;     // 65536
    float* w_x2   = ws + 823296;     // 65536
    float* w_part = ws + 888832;     // 16*128*2048 = 4194304 max

    // front-end scratch reuses the w_part region (free until the GEMM phase)
    float* w_gi = w_part;            // 128*768
    float* w_gh = w_part + 98304;    // 128*768

    hipLaunchKernelGGL(k1b_fused, dim3(3, 64), dim3(256), 0, stream,
                       pre, cvec, ah_in, fc1W, fc1b, fc2W, fc2b,
                       gWih, gWhh, gbih, gbhh, w_gi, w_gh);

    hipLaunchKernelGGL(k1c_gates_q, dim3(128), dim3(256), 0, stream,
                       w_gi, w_gh, ah_in, attnW, o_attnh, w_q);

    hipLaunchKernelGGL(ka_attn, dim3(2048), dim3(256), 0, stream,
                       encp, enc, w_q, attnv, w_u, w_ctxp, w_m, w_s);

    hipLaunchKernelGGL(kb_combine, dim3(128), dim3(256), 0, stream,
                       w_u, w_m, w_s, w_ctxp, o_attnh, o_scor, o_ctx, w_cat1);

    // rnn_in: K=512, 16 k-slices -> 256 blocks
    hipLaunchKernelGGL(gemm512_splitk, dim3(8, 2, 16), dim3(256), 0, stream,
                       w_cat1, rinW, w_cat1, rinW, w_part, 512, 16);
    hipLaunchKernelGGL(e_rnn, dim3(256), dim3(256), 0, stream, w_part, rinb, w_x);

    // LSTM 1: 2 segments x 8 k-slices -> 1024 blocks (4/CU)
    hipLaunchKernelGGL(gemm512_splitk, dim3(32, 2, 16), dim3(256), 0, stream,
                       w_x, l1Wih, r1h, l1Whh, w_part, 2048, 8);
    hipLaunchKernelGGL(e_lstm, dim3(256), dim3(256), 0, stream,
                       w_part, l1bih, l1bhh, r1c, w_x, o_r1h, o_r1c, w_x2);

    // LSTM 2 + mel
    hipLaunchKernelGGL(gemm512_splitk, dim3(32, 2, 16), dim3(256), 0, stream,
                       w_x2, l2Wih, r2h, l2Whh, w_part, 2048, 8);
    hipLaunchKernelGGL(e_lstm2_mel, dim3(128), dim3(512), 0, stream,
                       w_part, l2bih, l2bhh, r2c, w_x2, melW, rp,
                       o_r2h, o_r2c, o_mels);
}

// Round 13
// 143.904 us; speedup vs baseline: 1.0255x; 1.0009x over previous
//
#include <hip/hip_runtime.h>
#include <math.h>

#define B_   128
#define T_   1024
#define D_   256
#define L_   512

__device__ __forceinline__ float sigmoidf_(float x) {
    return 1.f / (1.f + __expf(-x));
}
__device__ __forceinline__ float tanhf_(float x) {
    x = fminf(fmaxf(x, -15.f), 15.f);
    float e = __expf(2.f * x);
    return (e - 1.f) / (e + 1.f);
}
// tanh(x) = 1 - 2/(exp(2x)+1); exact identity, v_exp + v_rcp
__device__ __forceinline__ float tanh_fast(float x) {
    float e = __expf(2.f * x);
    return 1.f - 2.f * __builtin_amdgcn_rcpf(e + 1.f);
}
__device__ __forceinline__ float waveReduceSum(float v) {
    #pragma unroll
    for (int o = 32; o > 0; o >>= 1) v += __shfl_xor(v, o, 64);
    return v;
}

// non-temporal float4 load: no-L3-allocate stream (protects encp residency)
typedef float f4v __attribute__((ext_vector_type(4)));
__device__ __forceinline__ float4 nt_load4(const float4* p) {
    f4v v = __builtin_nontemporal_load((const f4v*)p);
    return make_float4(v.x, v.y, v.z, v.w);
}

// ---------------------------------------------------------------------------
// K1b fused: prenet (recomputed per block, cheap) + GRU gate GEMVs.
// grid = (3 j-tiles, 64 batch-pairs), block = 256.
// ---------------------------------------------------------------------------
__global__ __launch_bounds__(256) void k1b_fused(
    const float* __restrict__ prenet_in, const float* __restrict__ context_vec,
    const float* __restrict__ attn_hidden,
    const float* __restrict__ fc1_W, const float* __restrict__ fc1_b,
    const float* __restrict__ fc2_W, const float* __restrict__ fc2_b,
    const float* __restrict__ gru_Wih, const float* __restrict__ gru_Whh,
    const float* __restrict__ gru_bih, const float* __restrict__ gru_bhh,
    float* __restrict__ gi_out, float* __restrict__ gh_out)
{
    const int t = threadIdx.x;
    const int j = blockIdx.x * 256 + t;
    const int b0 = blockIdx.y * 2;

    __shared__ __align__(16) float pin[2][80];
    __shared__ __align__(16) float p1[2][256];
    __shared__ __align__(16) float xs[2][384];   // [cvec | prenet_out]
    __shared__ __align__(16) float hs[2][256];

    if (t < 160) pin[t / 80][t % 80] = prenet_in[(b0 + t / 80) * 80 + (t % 80)];
    xs[0][t] = context_vec[b0 * 256 + t];
    xs[1][t] = context_vec[(b0 + 1) * 256 + t];
    hs[0][t] = attn_hidden[b0 * 256 + t];
    hs[1][t] = attn_hidden[(b0 + 1) * 256 + t];
    __syncthreads();

    // fc1: 256 outputs x 2 batches, K=80
    {
        float a0 = fc1_b[t], a1 = a0;
        const float4* w  = (const float4*)(fc1_W + t * 80);
        const float4* x0 = (const float4*)pin[0];
        const float4* x1 = (const float4*)pin[1];
        #pragma unroll
        for (int k = 0; k < 20; k++) {
            float4 wv = w[k], v0 = x0[k], v1 = x1[k];
            a0 += v0.x * wv.x + v0.y * wv.y + v0.z * wv.z + v0.w * wv.w;
            a1 += v1.x * wv.x + v1.y * wv.y + v1.z * wv.z + v1.w * wv.w;
        }
        p1[0][t] = fmaxf(a0, 0.f);
        p1[1][t] = fmaxf(a1, 0.f);
    }
    __syncthreads();

    // fc2: 128 outputs x 2 batches, K=256 (t<128 -> batch0, t>=128 -> batch1)
    {
        const int bb = t >> 7, jj = t & 127;
        float a = fc2_b[jj];
        const float4* w  = (const float4*)(fc2_W + jj * 256);
        const float4* xv = (const float4*)p1[bb];
        #pragma unroll 8
        for (int k = 0; k < 64; k++) {
            float4 wv = w[k], v = xv[k];
            a += v.x * wv.x + v.y * wv.y + v.z * wv.z + v.w * wv.w;
        }
        xs[bb][256 + jj] = fmaxf(a, 0.f);
    }
    __syncthreads();

    // gi: K=384
    {
        float a0 = gru_bih[j], a1 = a0;
        const float4* w  = (const float4*)(gru_Wih + (size_t)j * 384);
        const float4* x0 = (const float4*)xs[0];
        const float4* x1 = (const float4*)xs[1];
        #pragma unroll 8
        for (int k = 0; k < 96; k++) {
            float4 wv = w[k], v0 = x0[k], v1 = x1[k];
            a0 += v0.x * wv.x + v0.y * wv.y + v0.z * wv.z + v0.w * wv.w;
            a1 += v1.x * wv.x + v1.y * wv.y + v1.z * wv.z + v1.w * wv.w;
        }
        gi_out[(size_t)(b0 + 0) * 768 + j] = a0;
        gi_out[(size_t)(b0 + 1) * 768 + j] = a1;
    }
    // gh: K=256
    {
        float a0 = gru_bhh[j], a1 = a0;
        const float4* w  = (const float4*)(gru_Whh + (size_t)j * 256);
        const float4* x0 = (const float4*)hs[0];
        const float4* x1 = (const float4*)hs[1];
        #pragma unroll 8
        for (int k = 0; k < 64; k++) {
            float4 wv = w[k], v0 = x0[k], v1 = x1[k];
            a0 += v0.x * wv.x + v0.y * wv.y + v0.z * wv.z + v0.w * wv.w;
            a1 += v1.x * wv.x + v1.y * wv.y + v1.z * wv.z + v1.w * wv.w;
        }
        gh_out[(size_t)(b0 + 0) * 768 + j] = a0;
        gh_out[(size_t)(b0 + 1) * 768 + j] = a1;
    }
}

// ---------------------------------------------------------------------------
// K1c: GRU gates + q = attn_h @ attn_W.T.   grid=128, block=256
// ---------------------------------------------------------------------------
__global__ __launch_bounds__(256) void k1c_gates_q(
    const float* __restrict__ gi, const float* __restrict__ gh,
    const float* __restrict__ attn_hidden, const float* __restrict__ attn_W,
    float* __restrict__ attn_h_out, float* __restrict__ q_out)
{
    const int b = blockIdx.x, t = threadIdx.x;
    __shared__ __align__(16) float ahn[256];

    {
        float hp = attn_hidden[b * 256 + t];
        float rg = sigmoidf_(gi[(size_t)b * 768 + t]       + gh[(size_t)b * 768 + t]);
        float zg = sigmoidf_(gi[(size_t)b * 768 + 256 + t] + gh[(size_t)b * 768 + 256 + t]);
        float ng = tanhf_(gi[(size_t)b * 768 + 512 + t] + rg * gh[(size_t)b * 768 + 512 + t]);
        float h  = (1.f - zg) * ng + zg * hp;
        ahn[t] = h;
        attn_h_out[b * 256 + t] = h;
    }
    __syncthreads();

    {
        float a = 0.f;
        const float4* w  = (const float4*)(attn_W + (size_t)t * 256);
        const float4* xv = (const float4*)ahn;
        #pragma unroll 8
        for (int k = 0; k < 64; k++) {
            float4 wv = w[k], v = xv[k];
            a += v.x * wv.x + v.y * wv.y + v.z * wv.z + v.w * wv.w;
        }
        q_out[b * 256 + t] = a;
    }
}

// ---------------------------------------------------------------------------
// KA: fused attention, STREAM-OVERLAPPED per 4-row pass (no-max softmax:
// |u| <= sum|v| ~ 10, fp32-safe; validated R5/R7/R8).
//  Per pass: issue 4 enc nt loads (depend on nothing) -> compute 4 u's from
//  L3-resident encp (16-lane groups) -> shfl-broadcast e -> FMA arrived enc.
//  No barriers in the main loop; single block reduce at the end.
// grid = B*16 chunks of 64 t, block=256 (4 waves, wave owns 16 rows).
// ---------------------------------------------------------------------------
__global__ __launch_bounds__(256, 4) void ka_attn(
    const float* __restrict__ enc_proj, const float* __restrict__ enc,
    const float* __restrict__ q, const float* __restrict__ v,
    float* __restrict__ u_out, float* __restrict__ ctx_part,
    float* __restrict__ s_part)
{
    const int b     = blockIdx.x >> 4;
    const int chunk = blockIdx.x & 15;
    const int tid   = threadIdx.x;
    const int lane  = tid & 63;
    const int wv    = tid >> 6;    // 0..3
    const int g     = lane >> 4;   // 16-lane group 0..3
    const int gl    = lane & 15;

    __shared__ __align__(16) float4 red[4][64];
    __shared__ float sred[4];

    const int t0 = chunk * 64;

    // per-lane copies of q,v covering all 4 d-chunks of 64
    float4 qv[4], vv[4];
    #pragma unroll
    for (int c = 0; c < 4; c++) {
        qv[c] = ((const float4*)(q + b * 256))[c * 16 + gl];
        vv[c] = ((const float4*)v)[c * 16 + gl];
    }

    const float*  pbase = enc_proj + ((size_t)(b * T_ + t0)) * 256;
    const float4* enc4  = (const float4*)(enc + ((size_t)(b * T_ + t0)) * 256);

    float4 acc0 = {0.f, 0.f, 0.f, 0.f}, acc1 = {0.f, 0.f, 0.f, 0.f};
    float s_acc = 0.f;

    #pragma unroll
    for (int pass = 0; pass < 4; pass++) {
        const int r0 = wv * 16 + pass * 4;

        // --- issue enc nt loads FIRST (independent of u) ---
        float4 ev0 = nt_load4(&enc4[(size_t)(r0 + 0) * 64 + lane]);
        float4 ev1 = nt_load4(&enc4[(size_t)(r0 + 1) * 64 + lane]);
        float4 ev2 = nt_load4(&enc4[(size_t)(r0 + 2) * 64 + lane]);
        float4 ev3 = nt_load4(&enc4[(size_t)(r0 + 3) * 64 + lane]);

        // --- u for row r0+g (16-lane group), encp from L3 ---
        const float4* row = (const float4*)(pbase + (size_t)(r0 + g) * 256);
        float s = 0.f;
        #pragma unroll
        for (int c = 0; c < 4; c++) {
            float4 pj = row[c * 16 + gl];
            s += tanh_fast(pj.x + qv[c].x) * vv[c].x
               + tanh_fast(pj.y + qv[c].y) * vv[c].y
               + tanh_fast(pj.z + qv[c].z) * vv[c].z
               + tanh_fast(pj.w + qv[c].w) * vv[c].w;
        }
        s += __shfl_xor(s, 1, 64);
        s += __shfl_xor(s, 2, 64);
        s += __shfl_xor(s, 4, 64);
        s += __shfl_xor(s, 8, 64);
        if (gl == 0) u_out[b * T_ + t0 + r0 + g] = s;

        // broadcast each group's u to the whole wave, exponentiate
        float e0 = __expf(__shfl(s,  0, 64));
        float e1 = __expf(__shfl(s, 16, 64));
        float e2 = __expf(__shfl(s, 32, 64));
        float e3 = __expf(__shfl(s, 48, 64));
        s_acc += (e0 + e1) + (e2 + e3);

        // --- FMA the (now arrived) enc rows ---
        acc0.x += e0 * ev0.x; acc0.y += e0 * ev0.y; acc0.z += e0 * ev0.z; acc0.w += e0 * ev0.w;
        acc1.x += e1 * ev1.x; acc1.y += e1 * ev1.y; acc1.z += e1 * ev1.z; acc1.w += e1 * ev1.w;
        acc0.x += e2 * ev2.x; acc0.y += e2 * ev2.y; acc0.z += e2 * ev2.z; acc0.w += e2 * ev2.w;
        acc1.x += e3 * ev3.x; acc1.y += e3 * ev3.y; acc1.z += e3 * ev3.z; acc1.w += e3 * ev3.w;
    }
    acc0.x += acc1.x; acc0.y += acc1.y; acc0.z += acc1.z; acc0.w += acc1.w;

    red[wv][lane] = acc0;
    if (lane == 0) sred[wv] = s_acc;   // s_acc uniform across the wave
    __syncthreads();

    if (tid < 64) {
        float4 s = red[0][tid];
        float4 a1 = red[1][tid], a2 = red[2][tid], a3 = red[3][tid];
        s.x += a1.x + a2.x + a3.x;
        s.y += a1.y + a2.y + a3.y;
        s.z += a1.z + a2.z + a3.z;
        s.w += a1.w + a2.w + a3.w;
        ((float4*)ctx_part)[(size_t)(b * 16 + chunk) * 64 + tid] = s;
    }
    if (tid == 0)
        s_part[b * 16 + chunk] = sred[0] + sred[1] + sred[2] + sred[3];
}

// ---------------------------------------------------------------------------
// KB: combine 16 partials -> context, scores, concat1 (no-max softmax).
// grid=128 (per batch)
// ---------------------------------------------------------------------------
__global__ __launch_bounds__(256) void kb_combine(
    const float* __restrict__ u, const float* __restrict__ s_part,
    const float* __restrict__ ctx_part, const float* __restrict__ attn_h,
    float* __restrict__ scores_out, float* __restrict__ ctx_out,
    float* __restrict__ concat1)
{
    const int b = blockIdx.x, tid = threadIdx.x;
    __shared__ float ssh[16];
    if (tid < 16) ssh[tid] = s_part[b * 16 + tid];
    __syncthreads();

    float S = 0.f;
    #pragma unroll
    for (int c = 0; c < 16; c++) S += ssh[c];
    float invS = 1.f / S;

    {
        float a = 0.f;
        #pragma unroll
        for (int c = 0; c < 16; c++)
            a += ctx_part[(size_t)(b * 16 + c) * 256 + tid];
        a *= invS;
        ctx_out[b * 256 + tid] = a;
        concat1[b * 512 + tid] = a;
        concat1[b * 512 + 256 + tid] = attn_h[b * 256 + tid];
    }

    #pragma unroll
    for (int i = 0; i < 4; i++) {
        int t = i * 256 + tid;
        scores_out[b * T_ + t] = __expf(u[b * T_ + t]) * invS;
    }
}

// ---------------------------------------------------------------------------
// GEMM: part[z][m][n] = A_seg[m][k0:k0+KSZ] @ W_seg[n][k0:k0+KSZ]^T
// grid = (N/64, 2, nseg*ksPerSeg)
// ---------------------------------------------------------------------------
__global__ __launch_bounds__(256) void gemm512_splitk(
    const float* __restrict__ A1, const float* __restrict__ W1,
    const float* __restrict__ A2, const float* __restrict__ W2,
    float* __restrict__ part, int N, int ksPerSeg)
{
    const int n0 = blockIdx.x * 64, m0 = blockIdx.y * 64;
    const int seg = blockIdx.z / ksPerSeg, ls = blockIdx.z % ksPerSeg;
    const int KSZ = 512 / ksPerSeg;
    const float* A = seg ? A2 : A1;
    const float* W = seg ? W2 : W1;
    const int k0 = ls * KSZ;

    __shared__ __align__(16) float As[32][68];
    __shared__ __align__(16) float Ws[32][68];

    const int tid = threadIdx.x;
    const int tm = tid & 15, tn = tid >> 4;
    const int rs = tid >> 3, qs = tid & 7;

    float acc[4][4] = {};

    for (int kt = 0; kt < KSZ; kt += 32) {
        #pragma unroll
        for (int it = 0; it < 2; it++) {
            int r = rs + it * 32;
            float4 av = *(const float4*)(A + (size_t)(m0 + r) * 512 + k0 + kt + qs * 4);
            As[qs * 4 + 0][r] = av.x; As[qs * 4 + 1][r] = av.y;
            As[qs * 4 + 2][r] = av.z; As[qs * 4 + 3][r] = av.w;
            float4 wv = *(const float4*)(W + (size_t)(n0 + r) * 512 + k0 + kt + qs * 4);
            Ws[qs * 4 + 0][r] = wv.x; Ws[qs * 4 + 1][r] = wv.y;
            Ws[qs * 4 + 2][r] = wv.z; Ws[qs * 4 + 3][r] = wv.w;
        }
        __syncthreads();
        #pragma unroll
        for (int kk = 0; kk < 32; kk++) {
            float4 a = *(const float4*)&As[kk][tm * 4];
            float4 w = *(const float4*)&Ws[kk][tn * 4];
            acc[0][0] += a.x * w.x; acc[0][1] += a.x * w.y; acc[0][2] += a.x * w.z; acc[0][3] += a.x * w.w;
            acc[1][0] += a.y * w.x; acc[1][1] += a.y * w.y; acc[1][2] += a.y * w.z; acc[1][3] += a.y * w.w;
            acc[2][0] += a.z * w.x; acc[2][1] += a.z * w.y; acc[2][2] += a.z * w.z; acc[2][3] += a.z * w.w;
            acc[3][0] += a.w * w.x; acc[3][1] += a.w * w.y; acc[3][2] += a.w * w.z; acc[3][3] += a.w * w.w;
        }
        __syncthreads();
    }

    float* pb = part + ((size_t)blockIdx.z * 128 + m0) * N + n0;
    #pragma unroll
    for (int i = 0; i < 4; i++) {
        float4 o = {acc[i][0], acc[i][1], acc[i][2], acc[i][3]};
        *(float4*)(pb + (size_t)(tm * 4 + i) * N + tn * 4) = o;
    }
}

// ---------------------------------------------------------------------------
// E_rnn: x = sum_z part[z] + bias     (N=512, 16 slices)
// ---------------------------------------------------------------------------
__global__ __launch_bounds__(256) void e_rnn(
    const float* __restrict__ part, const float* __restrict__ bias,
    float* __restrict__ x)
{
    const int idx = blockIdx.x * 256 + threadIdx.x;
    const int n = idx & 511;
    float a = bias[n];
    #pragma unroll
    for (int z = 0; z < 16; z++) a += part[(size_t)z * 65536 + idx];
    x[idx] = a;
}

// ---------------------------------------------------------------------------
// E_lstm: gate reduce (16 slices, N=2048) + LSTM cell + x_new = x_prev + h
// ---------------------------------------------------------------------------
__global__ __launch_bounds__(256) void e_lstm(
    const float* __restrict__ part,
    const float* __restrict__ bih, const float* __restrict__ bhh,
    const float* __restrict__ c_prev, const float* __restrict__ x_prev,
    float* __restrict__ h_out, float* __restrict__ c_out, float* __restrict__ x_new)
{
    const int idx = blockIdx.x * 256 + threadIdx.x;
    const int bb = idx >> 9, j = idx & 511;
    float gi = bih[j] + bhh[j];
    float gf = bih[512 + j] + bhh[512 + j];
    float gg = bih[1024 + j] + bhh[1024 + j];
    float go = bih[1536 + j] + bhh[1536 + j];
    #pragma unroll
    for (int z = 0; z < 16; z++) {
        const float* p = part + ((size_t)z * 128 + bb) * 2048;
        gi += p[j]; gf += p[512 + j]; gg += p[1024 + j]; go += p[1536 + j];
    }
    float c = sigmoidf_(gf) * c_prev[idx] + sigmoidf_(gi) * tanhf_(gg);
    float h = sigmoidf_(go) * tanhf_(c);
    h_out[idx] = h;
    c_out[idx] = c;
    x_new[idx] = x_prev[idx] + h;
}

// ---------------------------------------------------------------------------
// E_lstm2 + mel: grid=128 (per batch), block=512. x3 stays in LDS.
// ---------------------------------------------------------------------------
__global__ __launch_bounds__(512) void e_lstm2_mel(
    const float* __restrict__ part,
    const float* __restrict__ bih, const float* __restrict__ bhh,
    const float* __restrict__ c_prev, const float* __restrict__ x_prev,
    const float* __restrict__ mel_W, const int* __restrict__ r_ptr,
    float* __restrict__ h_out, float* __restrict__ c_out,
    float* __restrict__ mels)
{
    const int b = blockIdx.x, j = threadIdx.x;
    __shared__ __align__(16) float xs[512];

    const int idx = b * 512 + j;
    float gi = bih[j] + bhh[j];
    float gf = bih[512 + j] + bhh[512 + j];
    float gg = bih[1024 + j] + bhh[1024 + j];
    float go = bih[1536 + j] + bhh[1536 + j];
    #pragma unroll
    for (int z = 0; z < 16; z++) {
        const float* p = part + ((size_t)z * 128 + b) * 2048;
        gi += p[j]; gf += p[512 + j]; gg += p[1024 + j]; go += p[1536 + j];
    }
    float c = sigmoidf_(gf) * c_prev[idx] + sigmoidf_(gi) * tanhf_(gg);
    float h = sigmoidf_(go) * tanhf_(c);
    h_out[idx] = h;
    c_out[idx] = c;
    xs[j] = x_prev[idx] + h;
    __syncthreads();

    const int r = r_ptr[0];
    const int tot = 80 * r;
    for (int n = j; n < tot; n += 512) {
        int m = n / r, rr = n % r;
        const float4* w  = (const float4*)(mel_W + (size_t)(m * 20 + rr) * 512);
        const float4* xv = (const float4*)xs;
        float a = 0.f;
        #pragma unroll 8
        for (int k = 0; k < 128; k++) {
            float4 wv = w[k], vv = xv[k];
            a += wv.x * vv.x + wv.y * vv.y + wv.z * vv.z + wv.w * vv.w;
        }
        mels[(size_t)b * tot + n] = a;
    }
}

// ---------------------------------------------------------------------------
extern "C" void kernel_launch(void* const* d_in, const int* in_sizes, int n_in,
                              void* d_out, int out_size, void* d_ws, size_t ws_size,
                              hipStream_t stream)
{
    const float* enc   = (const float*)d_in[0];
    const float* encp  = (const float*)d_in[1];
    const float* pre   = (const float*)d_in[2];
    const float* ah_in = (const float*)d_in[3];
    const float* r1h   = (const float*)d_in[4];
    const float* r2h   = (const float*)d_in[5];
    const float* r1c   = (const float*)d_in[6];
    const float* r2c   = (const float*)d_in[7];
    const float* cvec  = (const float*)d_in[8];
    const float* fc1W  = (const float*)d_in[9];
    const float* fc1b  = (const float*)d_in[10];
    const float* fc2W  = (const float*)d_in[11];
    const float* fc2b  = (const float*)d_in[12];
    const float* attnW = (const float*)d_in[13];
    const float* attnv = (const float*)d_in[14];
    const float* gWih  = (const float*)d_in[15];
    const float* gWhh  = (const float*)d_in[16];
    const float* gbih  = (const float*)d_in[17];
    const float* gbhh  = (const float*)d_in[18];
    const float* rinW  = (const float*)d_in[19];
    const float* rinb  = (const float*)d_in[20];
    const float* l1Wih = (const float*)d_in[21];
    const float* l1Whh = (const float*)d_in[22];
    const float* l1bih = (const float*)d_in[23];
    const float* l1bhh = (const float*)d_in[24];
    const float* l2Wih = (const float*)d_in[25];
    const float* l2Whh = (const float*)d_in[26];
    const float* l2bih = (const float*)d_in[27];
    const float* l2bhh = (const float*)d_in[28];
    const float* melW  = (const float*)d_in[29];
    const int*   rp    = (const int*)d_in[30];

    float* out = (float*)d_out;
    float* o_mels  = out + 0;        // 128*80*2
    float* o_scor  = out + 20480;    // 128*1024
    float* o_attnh = out + 151552;   // 128*256
    float* o_r1h   = out + 184320;   // 128*512
    float* o_r2h   = out + 249856;
    float* o_r1c   = out + 315392;
    float* o_r2c   = out + 380928;
    float* o_ctx   = out + 446464;   // 128*256

    float* ws     = (float*)d_ws;
    float* w_q    = ws + 0;          // 32768
    float* w_u    = ws + 32768;      // 131072
    float* w_s    = ws + 163840;     // 2048
    float* w_ctxp = ws + 165888;     // 16*128*256 = 524288
    float* w_cat1 = ws + 692224;     // 65536
    float* w_x    = ws + 757760;     // 65536
    float* w_x2   = ws + 823296;     // 65536
    float* w_part = ws + 888832;     // 16*128*2048 = 4194304 max

    // front-end scratch reuses the w_part region (free until the GEMM phase)
    float* w_gi = w_part;            // 128*768
    float* w_gh = w_part + 98304;    // 128*768

    hipLaunchKernelGGL(k1b_fused, dim3(3, 64), dim3(256), 0, stream,
                       pre, cvec, ah_in, fc1W, fc1b, fc2W, fc2b,
                       gWih, gWhh, gbih, gbhh, w_gi, w_gh);

    hipLaunchKernelGGL(k1c_gates_q, dim3(128), dim3(256), 0, stream,
                       w_gi, w_gh, ah_in, attnW, o_attnh, w_q);

    hipLaunchKernelGGL(ka_attn, dim3(2048), dim3(256), 0, stream,
                       encp, enc, w_q, attnv, w_u, w_ctxp, w_s);

    hipLaunchKernelGGL(kb_combine, dim3(128), dim3(256), 0, stream,
                       w_u, w_s, w_ctxp, o_attnh, o_scor, o_ctx, w_cat1);

    // rnn_in: K=512, 16 k-slices -> 256 blocks
    hipLaunchKernelGGL(gemm512_splitk, dim3(8, 2, 16), dim3(256), 0, stream,
                       w_cat1, rinW, w_cat1, rinW, w_part, 512, 16);
    hipLaunchKernelGGL(e_rnn, dim3(256), dim3(256), 0, stream, w_part, rinb, w_x);

    // LSTM 1: 2 segments x 8 k-slices -> 1024 blocks (4/CU)
    hipLaunchKernelGGL(gemm512_splitk, dim3(32, 2, 16), dim3(256), 0, stream,
                       w_x, l1Wih, r1h, l1Whh, w_part, 2048, 8);
    hipLaunchKernelGGL(e_lstm, dim3(256), dim3(256), 0, stream,
                       w_part, l1bih, l1bhh, r1c, w_x, o_r1h, o_r1c, w_x2);

    // LSTM 2 + mel
    hipLaunchKernelGGL(gemm512_splitk, dim3(32, 2, 16), dim3(256), 0, stream,
                       w_x2, l2Wih, r2h, l2Whh, w_part, 2048, 8);
    hipLaunchKernelGGL(e_lstm2_mel, dim3(128), dim3(512), 0, stream,
                       w_part, l2bih, l2bhh, r2c, w_x2, melW, rp,
                       o_r2h, o_r2c, o_mels);
}